// Round 19
// baseline (198.202 us; speedup 1.0000x reference)
//
#include <hip/hip_runtime.h>

#define SEQ    2048
#define DIN    2048
#define DMODEL 1024
#define NROWS  4096   // BATCH*SEQ
#define NCH    32     // scan chunks
#define CHL    64     // chunk length

typedef __attribute__((ext_vector_type(8))) _Float16 half8v;
typedef __attribute__((ext_vector_type(8))) unsigned short ushort8v;
typedef __attribute__((ext_vector_type(4))) float f32x4;

__device__ __forceinline__ float sigf(float x) { return 1.0f / (1.0f + __expf(-x)); }
// inline softplus: no libm call (log1pf is a non-inlined OCML slow path — was a 100 µs pathology)
__device__ __forceinline__ float softplusf(float v) {
    return fmaxf(v, 0.f) + __logf(1.f + __expf(-fabsf(v)));
}

__device__ __forceinline__ void gload16(const void* g, const void* l) {
    __builtin_amdgcn_global_load_lds((const __attribute__((address_space(1))) void*)g,
                                     (__attribute__((address_space(3))) void*)l, 16, 0, 0);
}

__device__ __forceinline__ unsigned short f2h(float x) {
    _Float16 h = (_Float16)x;           // v_cvt_f16_f32, RNE
    unsigned short u;
    __builtin_memcpy(&u, &h, 2);
    return u;
}
__device__ __forceinline__ float h2f(unsigned short u) {
    _Float16 h;
    __builtin_memcpy(&h, &u, 2);
    return (float)h;
}

// ---------------- fused fp32 -> fp16 convert: x, wi, Wx(pad 128), wd, wo ----------------
__global__ __launch_bounds__(256) void cvt_in_k(
    const float* __restrict__ x, const float* __restrict__ wi, const float* __restrict__ wx,
    const float* __restrict__ wd, const float* __restrict__ wo,
    unsigned short* __restrict__ xh, unsigned short* __restrict__ wih,
    unsigned short* __restrict__ wxh, unsigned short* __restrict__ wdh,
    unsigned short* __restrict__ woh)
{
    int i = blockIdx.x * 256 + threadIdx.x;    // 2719744 total float4s
    if (i < 1048576) {
        float4 v = ((const float4*)x)[i];
        ushort4 h; h.x = f2h(v.x); h.y = f2h(v.y); h.z = f2h(v.z); h.w = f2h(v.w);
        ((ushort4*)xh)[i] = h;
    } else if (i < 2097152) {
        i -= 1048576;
        float4 v = ((const float4*)wi)[i];
        ushort4 h; h.x = f2h(v.x); h.y = f2h(v.y); h.z = f2h(v.z); h.w = f2h(v.w);
        ((ushort4*)wih)[i] = h;
    } else if (i < 2162688) {
        i -= 2097152;
        int row = i >> 9, q = i & 511;        // [128][512 x float4]
        ushort4 h;
        if (row < 96) {
            float4 v = ((const float4*)wx)[(size_t)row * 512 + q];
            h.x = f2h(v.x); h.y = f2h(v.y); h.z = f2h(v.z); h.w = f2h(v.w);
        } else h = make_ushort4(0, 0, 0, 0);
        ((ushort4*)wxh)[(size_t)row * 512 + q] = h;
    } else if (i < 2195456) {
        i -= 2162688;                          // wd: 2048x64 dense
        float4 v = ((const float4*)wd)[i];
        ushort4 h; h.x = f2h(v.x); h.y = f2h(v.y); h.z = f2h(v.z); h.w = f2h(v.w);
        ((ushort4*)wdh)[i] = h;
    } else {
        i -= 2195456;                          // wo: 1024x2048
        float4 v = ((const float4*)wo)[i];
        ushort4 h; h.x = f2h(v.x); h.y = f2h(v.y); h.z = f2h(v.z); h.w = f2h(v.w);
        ((ushort4*)woh)[i] = h;
    }
}

// ======== in_proj GEMM: 256x128 tile, single-buffer 48 KiB LDS, 512 blocks (2/CU) ======
__global__ __launch_bounds__(512, 4) void gemm_inproj(
    const unsigned short* __restrict__ A, const unsigned short* __restrict__ W,
    unsigned short* __restrict__ C, int K, int N, int mtiles, int lda, int ldw)
{
    __shared__ uint4 ldsu4[3072];          // 48 KiB: A[256][64] @0, B[128][64] @32768
    char* lds = (char*)ldsu4;
    const int tid = threadIdx.x;
    const int w = tid >> 6, lane = tid & 63;

    const int nwg = gridDim.x;
    const int cpx = nwg >> 3;
    const int bid = blockIdx.x;
    const int swz = (bid & 7) * cpx + (bid >> 3);
    const int ntiles = nwg / mtiles;
    const int per = 8 * ntiles;
    const int gid = swz / per;
    const int rem = swz - gid * per;
    const int m0 = (gid * 8 + (rem & 7)) * 256;
    const int n0 = (rem >> 3) * 128;

    const int wr = w >> 2, wc = w & 3;     // wave tile: 128 x 32
    const int lm = lane & 15, lk = lane >> 4;

    f32x4 acc[8][2];
#pragma unroll
    for (int i = 0; i < 8; ++i)
#pragma unroll
        for (int j = 0; j < 2; ++j) { acc[i][j][0]=0.f; acc[i][j][1]=0.f; acc[i][j][2]=0.f; acc[i][j][3]=0.f; }

    const int rsub = w * 8 + (lane >> 3);
    const int xr8  = ((lane & 7) ^ (lane >> 3)) << 3;   // pre-swizzled col chunk
    const unsigned short* gA = A + (size_t)(m0 + rsub) * lda + xr8;
    const unsigned short* gW = W + (size_t)(n0 + rsub) * ldw + xr8;
    const int sdst = w * 1024;                           // + lane*16 appended by HW

    for (int kt = 0; kt < K; kt += 64) {
#pragma unroll
        for (int i = 0; i < 4; ++i)
            gload16(gA + (size_t)i * 64 * lda + kt, lds + i * 8192 + sdst);
#pragma unroll
        for (int i = 0; i < 2; ++i)
            gload16(gW + (size_t)i * 64 * ldw + kt, lds + 32768 + i * 8192 + sdst);
        __syncthreads();
#pragma unroll
        for (int kk = 0; kk < 2; ++kk) {
            half8v b[2];
#pragma unroll
            for (int nb = 0; nb < 2; ++nb) {
                const int br = wc * 32 + nb * 16 + lm;
                b[nb] = *(const half8v*)(lds + 32768 + br * 128 + (((kk * 4 + lk) ^ (br & 7)) << 4));
            }
            __builtin_amdgcn_s_setprio(1);
#pragma unroll
            for (int mb = 0; mb < 8; ++mb) {
                const int ar = wr * 128 + mb * 16 + lm;
                half8v a = *(const half8v*)(lds + ar * 128 + (((kk * 4 + lk) ^ (ar & 7)) << 4));
#pragma unroll
                for (int nb = 0; nb < 2; ++nb)
                    acc[mb][nb] = __builtin_amdgcn_mfma_f32_16x16x32_f16(a, b[nb], acc[mb][nb], 0, 0, 0);
            }
            __builtin_amdgcn_s_setprio(0);
        }
        __syncthreads();
    }

#pragma unroll
    for (int mb = 0; mb < 8; ++mb)
#pragma unroll
        for (int nb = 0; nb < 2; ++nb)
#pragma unroll
            for (int r = 0; r < 4; ++r)
                C[(size_t)(m0 + wr * 128 + mb * 16 + lk * 4 + r) * N + (n0 + wc * 32 + nb * 16 + lm)]
                    = f2h(acc[mb][nb][r]);
}

// ---------------- 128x128 fp16 MFMA GEMM, split-K, fp16 output ----------------
#define A_OFF 0
#define W_OFF 16384

__global__ __launch_bounds__(256) void gemm_mfma_h(
    const unsigned short* __restrict__ A, const unsigned short* __restrict__ W,
    unsigned short* __restrict__ C, int K, int ldc, int nmax, int mtiles,
    int sA1, int sA2, int ldw, const float* __restrict__ bias, int kspl, int cstride)
{
    __shared__ uint4 ldsu4[2048];
    char* lds = (char*)ldsu4;
    const int tid  = threadIdx.x;
    const int w    = tid >> 6, lane = tid & 63;

    const int nwg = gridDim.x;
    const int cpx = nwg >> 3;
    const int bid = blockIdx.x;
    const int swz = (bid & 7) * cpx + (bid >> 3);
    const int nbp = nwg / kspl;
    const int ks  = swz / nbp;
    const int tt  = swz - ks * nbp;
    const int ntiles = nbp / mtiles;
    const int per = 8 * ntiles;
    const int gid = tt / per;
    const int rem = tt - gid * per;
    const int m0 = (gid * 8 + (rem & 7)) * 128;
    const int n0 = (rem >> 3) * 128;
    const int kOff = ks * K;

    const int wr = w >> 1, wc = w & 1;

    f32x4 acc[4][4];
#pragma unroll
    for (int i = 0; i < 4; ++i)
#pragma unroll
        for (int j = 0; j < 4; ++j) { acc[i][j][0]=0.f; acc[i][j][1]=0.f; acc[i][j][2]=0.f; acc[i][j][3]=0.f; }

    const int rloc = w * 32 + (lane >> 3);
    const int xr8  = ((lane & 7) ^ (lane >> 3)) << 3;
    const int rowA = m0 + rloc;
    const unsigned short* gA = A + (size_t)(rowA >> 1) * sA2 + (size_t)(rowA & 1) * sA1 + kOff + xr8;
    const unsigned short* gW = W + (size_t)(n0 + rloc) * ldw + kOff + xr8;

    const int lm  = lane & 15;
    const int lk  = lane >> 4;
    const int lk4 = lk * 4;

    for (int kt = 0; kt < K; kt += 64) {
#pragma unroll
        for (int i = 0; i < 4; ++i) {
            const int rb = w * 32 + i * 8;
            gload16(gA + (size_t)i * 4 * sA2 + kt, lds + A_OFF + rb * 128);
            gload16(gW + (size_t)i * 8 * ldw + kt, lds + W_OFF + rb * 128);
        }
        __syncthreads();
#pragma unroll
        for (int h = 0; h < 2; ++h) {
            half8v af[4], wf[4];
            const int ch = h * 4 + lk;
#pragma unroll
            for (int t = 0; t < 4; ++t) {
                const int ar = wr * 64 + t * 16 + lm;
                const int wrw = wc * 64 + t * 16 + lm;
                af[t] = *(const half8v*)(lds + A_OFF + ar * 128 + ((ch ^ (ar & 7)) << 4));
                wf[t] = *(const half8v*)(lds + W_OFF + wrw * 128 + ((ch ^ (wrw & 7)) << 4));
            }
#pragma unroll
            for (int i = 0; i < 4; ++i)
#pragma unroll
                for (int j = 0; j < 4; ++j)
                    acc[i][j] = __builtin_amdgcn_mfma_f32_16x16x32_f16(af[i], wf[j], acc[i][j], 0, 0, 0);
        }
        __syncthreads();
    }

    unsigned short* Cp = C + (size_t)ks * cstride;
    if (bias) {
#pragma unroll
        for (int j = 0; j < 4; ++j) {
            const int n = n0 + wc * 64 + j * 16 + lm;
            const float bv = (n < nmax) ? bias[n] : 0.f;
#pragma unroll
            for (int i = 0; i < 4; ++i)
#pragma unroll
                for (int r = 0; r < 4; ++r) {
                    float v = acc[i][j][r] + bv;
                    if (n < nmax)
                        Cp[(size_t)(m0 + wr * 64 + i * 16 + lk4 + r) * ldc + n] = f2h(softplusf(v));
                }
        }
    } else {
#pragma unroll
        for (int i = 0; i < 4; ++i)
#pragma unroll
            for (int j = 0; j < 4; ++j) {
                const int n = n0 + wc * 64 + j * 16 + lm;
                if (n < nmax)
#pragma unroll
                    for (int r = 0; r < 4; ++r)
                        Cp[(size_t)(m0 + wr * 64 + i * 16 + lk4 + r) * ldc + n] = f2h(acc[i][j][r]);
            }
    }
}

// xproj reduce: sum 8 fp16 partials; cols 0..63 -> dlh fp16, cols 64..95 -> xdbl f32
__global__ __launch_bounds__(256) void xproj_reduce_k(
    const unsigned short* __restrict__ part, float* __restrict__ xdbl,
    unsigned short* __restrict__ dlh)
{
    int i = blockIdx.x * 256 + threadIdx.x;   // NROWS*32 quads
    if (i >= NROWS * 32) return;
    int row = i >> 5, q = i & 31;
    float s0 = 0.f, s1 = 0.f, s2 = 0.f, s3 = 0.f;
#pragma unroll
    for (int ks = 0; ks < 8; ++ks) {
        ushort4 v = *(const ushort4*)(part + (size_t)ks * (NROWS * 128) + (size_t)row * 128 + q * 4);
        s0 += h2f(v.x); s1 += h2f(v.y); s2 += h2f(v.z); s3 += h2f(v.w);
    }
    if (q < 16) {
        ushort4 h; h.x = f2h(s0); h.y = f2h(s1); h.z = f2h(s2); h.w = f2h(s3);
        *(ushort4*)(dlh + (size_t)row * 64 + q * 4) = h;
    } else {
        *(float4*)(xdbl + (size_t)row * 96 + q * 4) = make_float4(s0, s1, s2, s3);
    }
}

// out_proj partial reduce: out = p0 + p1 (fp16 partials -> f32 out)
__global__ __launch_bounds__(256) void out_reduce_k(
    const unsigned short* __restrict__ p, float* __restrict__ out)
{
    int i = blockIdx.x * 256 + threadIdx.x;   // 1048576 quads
    ushort4 a = ((const ushort4*)p)[i];
    ushort4 b = ((const ushort4*)(p + 4194304))[i];
    float4 v;
    v.x = h2f(a.x) + h2f(b.x);
    v.y = h2f(a.y) + h2f(b.y);
    v.z = h2f(a.z) + h2f(b.z);
    v.w = h2f(a.w) + h2f(b.w);
    ((float4*)out)[i] = v;
}

// ---------------- causal depthwise conv(4) + bias + SiLU, fp16 in -> fp16 out ----------
__global__ __launch_bounds__(256) void conv_silu_k(
    const unsigned short* __restrict__ xzh, const float* __restrict__ cw,
    const float* __restrict__ cb, unsigned short* __restrict__ xch)
{
    int i = blockIdx.x * 256 + threadIdx.x;   // NROWS*256
    int d8 = (i & 255) << 3;
    int row = i >> 8;
    int l = row & (SEQ - 1);
    const unsigned short* base = xzh + (size_t)row * 4096 + d8;
    ushort8v x0 = *(const ushort8v*)base;
    ushort8v x1 = {}, x2 = {}, x3 = {};
    if (l >= 1) x1 = *(const ushort8v*)(base - 4096);
    if (l >= 2) x2 = *(const ushort8v*)(base - 8192);
    if (l >= 3) x3 = *(const ushort8v*)(base - 12288);
    ushort8v out;
#pragma unroll
    for (int j = 0; j < 8; ++j) {
        float4 wv = *(const float4*)(cw + (size_t)(d8 + j) * 4);
        float a = cb[d8 + j];
        a = fmaf(h2f(x3[j]), wv.x, a);
        a = fmaf(h2f(x2[j]), wv.y, a);
        a = fmaf(h2f(x1[j]), wv.z, a);
        a = fmaf(h2f(x0[j]), wv.w, a);
        out[j] = f2h(a * sigf(a));
    }
    *(ushort8v*)(xch + (size_t)row * DIN + d8) = out;
}

// ---------------- chunked selective scan: register-resident 16-state, fp16 states ------
// A[n] = -(n+1) for the given inputs -> dA via power chain (1 exp + 15 muls),
// runtime-checked with 16-exp fallback.  Chunk states stored fp16 (|h| ~1e-2, ap in (0,1]).
__global__ __launch_bounds__(256) void scan_pass1(
    const unsigned short* __restrict__ dth, const unsigned short* __restrict__ xch,
    const float* __restrict__ xdbl, const float* __restrict__ Alog,
    unsigned short* __restrict__ hbuf, unsigned short* __restrict__ apbuf)
{
    const int b = blockIdx.z, c = blockIdx.y;
    const int d = blockIdx.x * 256 + threadIdx.x;
    float A[16];
#pragma unroll
    for (int q = 0; q < 4; ++q) *(float4*)&A[q * 4] = *(const float4*)&Alog[(size_t)d * 16 + q * 4];
    bool seq = true;
#pragma unroll
    for (int n = 0; n < 16; ++n) {
        A[n] = -__expf(A[n]);
        seq = seq && (fabsf(A[n] + (float)(n + 1)) < 1e-5f * (float)(n + 1));
    }
    float h[16] = {};
    float sumdt = 0.f;
    const int rowbase = b * SEQ + c * CHL;
    int row = rowbase;
    float dtv = h2f(dth[(size_t)row * DIN + d]);
    float xcv = h2f(xch[(size_t)row * DIN + d]);
    if (seq) {
        for (int t = 0; t < CHL; ++t) {
            const int nrow = row + ((t + 1) < CHL ? 1 : 0);
            float dtv2 = h2f(dth[(size_t)nrow * DIN + d]);
            float xcv2 = h2f(xch[(size_t)nrow * DIN + d]);
            const float* xr = xdbl + (size_t)row * 96;
            float u = dtv * xcv;
            sumdt += dtv;
            float r = __expf(-dtv);
            float dA = r;
#pragma unroll
            for (int n = 0; n < 16; ++n) {
                h[n] = fmaf(dA, h[n], u * xr[64 + n]);
                dA *= r;
            }
            dtv = dtv2; xcv = xcv2; row = nrow;
        }
    } else {
        for (int t = 0; t < CHL; ++t) {
            const int nrow = row + ((t + 1) < CHL ? 1 : 0);
            float dtv2 = h2f(dth[(size_t)nrow * DIN + d]);
            float xcv2 = h2f(xch[(size_t)nrow * DIN + d]);
            const float* xr = xdbl + (size_t)row * 96;
            float u = dtv * xcv;
            sumdt += dtv;
#pragma unroll
            for (int n = 0; n < 16; ++n) {
                float dA = __expf(dtv * A[n]);
                h[n] = fmaf(dA, h[n], u * xr[64 + n]);
            }
            dtv = dtv2; xcv = xcv2; row = nrow;
        }
    }
    float ap[16];
    if (seq) {
        float R = __expf(-sumdt);
        float a = R;
#pragma unroll
        for (int n = 0; n < 16; ++n) { ap[n] = a; a *= R; }
    } else {
#pragma unroll
        for (int n = 0; n < 16; ++n) ap[n] = __expf(sumdt * A[n]);
    }
    size_t e = ((size_t)(b * NCH + c) << 15) + (size_t)d * 16;
    ushort8v hv0, hv1, av0, av1;
#pragma unroll
    for (int n = 0; n < 8; ++n) {
        hv0[n] = f2h(h[n]);  hv1[n] = f2h(h[8 + n]);
        av0[n] = f2h(ap[n]); av1[n] = f2h(ap[8 + n]);
    }
    *(ushort8v*)(hbuf + e)      = hv0;
    *(ushort8v*)(hbuf + e + 8)  = hv1;
    *(ushort8v*)(apbuf + e)     = av0;
    *(ushort8v*)(apbuf + e + 8) = av1;
}

__global__ __launch_bounds__(256) void scan_pass2(
    unsigned short* __restrict__ hbuf, const unsigned short* __restrict__ apbuf)
{
    int idx = blockIdx.x * 256 + threadIdx.x;   // 65536
    int b = idx >> 15;
    int dn = idx & 32767;
    float carry = 0.f;
    for (int c = 0; c < NCH; ++c) {
        size_t e = ((size_t)(b * NCH + c) << 15) + dn;
        float hl = h2f(hbuf[e]);
        float ap = h2f(apbuf[e]);
        hbuf[e] = f2h(carry);
        carry = fmaf(ap, carry, hl);
    }
}

// pass 3: re-scan from h_in (fp16); fused epilogue writes op fp16 (dense [4096][2048])
__global__ __launch_bounds__(256) void scan_pass3(
    const unsigned short* __restrict__ dth, const unsigned short* __restrict__ xch,
    const unsigned short* __restrict__ xzh, const float* __restrict__ xdbl,
    const float* __restrict__ Alog, const float* __restrict__ Dp,
    const unsigned short* __restrict__ hbuf, unsigned short* __restrict__ oph)
{
    const int b = blockIdx.z, c = blockIdx.y;
    const int d = blockIdx.x * 256 + threadIdx.x;
    float A[16];
#pragma unroll
    for (int q = 0; q < 4; ++q) *(float4*)&A[q * 4] = *(const float4*)&Alog[(size_t)d * 16 + q * 4];
    bool seq = true;
#pragma unroll
    for (int n = 0; n < 16; ++n) {
        A[n] = -__expf(A[n]);
        seq = seq && (fabsf(A[n] + (float)(n + 1)) < 1e-5f * (float)(n + 1));
    }
    float h[16];
    size_t e = ((size_t)(b * NCH + c) << 15) + (size_t)d * 16;
    {
        ushort8v hv0 = *(const ushort8v*)(hbuf + e);
        ushort8v hv1 = *(const ushort8v*)(hbuf + e + 8);
#pragma unroll
        for (int n = 0; n < 8; ++n) { h[n] = h2f(hv0[n]); h[8 + n] = h2f(hv1[n]); }
    }
    const float Dd = Dp[d];
    const int rowbase = b * SEQ + c * CHL;
    int row = rowbase;
    float dtv = h2f(dth[(size_t)row * DIN + d]);
    float xcv = h2f(xch[(size_t)row * DIN + d]);
    float zv  = h2f(xzh[(size_t)row * 4096 + DIN + d]);
    if (seq) {
        for (int t = 0; t < CHL; ++t) {
            const int nrow = row + ((t + 1) < CHL ? 1 : 0);
            float dtv2 = h2f(dth[(size_t)nrow * DIN + d]);
            float xcv2 = h2f(xch[(size_t)nrow * DIN + d]);
            float zv2  = h2f(xzh[(size_t)nrow * 4096 + DIN + d]);
            const float* xr = xdbl + (size_t)row * 96;
            float u = dtv * xcv;
            float r = __expf(-dtv);
            float dA = r;
            float y = 0.f;
#pragma unroll
            for (int n = 0; n < 16; ++n) {
                h[n] = fmaf(dA, h[n], u * xr[64 + n]);
                y = fmaf(h[n], xr[80 + n], y);
                dA *= r;
            }
            float val = (y + xcv * Dd) * zv * sigf(zv);
            oph[(size_t)row * DIN + d] = f2h(val);
            dtv = dtv2; xcv = xcv2; zv = zv2; row = nrow;
        }
    } else {
        for (int t = 0; t < CHL; ++t) {
            const int nrow = row + ((t + 1) < CHL ? 1 : 0);
            float dtv2 = h2f(dth[(size_t)nrow * DIN + d]);
            float xcv2 = h2f(xch[(size_t)nrow * DIN + d]);
            float zv2  = h2f(xzh[(size_t)nrow * 4096 + DIN + d]);
            const float* xr = xdbl + (size_t)row * 96;
            float u = dtv * xcv;
            float y = 0.f;
#pragma unroll
            for (int n = 0; n < 16; ++n) {
                float dA = __expf(dtv * A[n]);
                h[n] = fmaf(dA, h[n], u * xr[64 + n]);
                y = fmaf(h[n], xr[80 + n], y);
            }
            float val = (y + xcv * Dd) * zv * sigf(zv);
            oph[(size_t)row * DIN + d] = f2h(val);
            dtv = dtv2; xcv = xcv2; zv = zv2; row = nrow;
        }
    }
}

extern "C" void kernel_launch(void* const* d_in, const int* in_sizes, int n_in,
                              void* d_out, int out_size, void* d_ws, size_t ws_size,
                              hipStream_t stream)
{
    const float* x    = (const float*)d_in[0];
    const float* wi   = (const float*)d_in[1];
    const float* cw   = (const float*)d_in[2];
    const float* cb   = (const float*)d_in[3];
    const float* wx   = (const float*)d_in[4];
    const float* wd   = (const float*)d_in[5];
    const float* bd   = (const float*)d_in[6];
    const float* alog = (const float*)d_in[7];
    const float* Dp   = (const float*)d_in[8];
    const float* wo   = (const float*)d_in[9];
    float* out = (float*)d_out;

    float* wsf  = (float*)d_ws;
    float* xzr  = wsf;                          // region 16,777,216 f32
    float* xcr  = wsf + 16777216;               // region  8,388,608 f32
    float* xdbl = wsf + 25165824;               // [4096][96] f32
    float* dtr  = wsf + 25559040;               // region  8,388,608 f32

    // xz region: fp16 xz [4096][4096] in first half; oph + hbuf in the second half
    unsigned short* xzh = (unsigned short*)xzr;
    float* scr = xzr + 8388608;
    unsigned short* oph  = (unsigned short*)scr;                // [4096][2048] fp16
    unsigned short* hbuf = (unsigned short*)(scr + 4194304);    // 2,097,152 fp16 chunk states

    // xc region: xch fp16 first half; apbuf above it
    unsigned short* xh    = (unsigned short*)xcr;               // in_proj A; dead after gemm
    unsigned short* xch   = (unsigned short*)xcr;               // conv output (overwrites xh)
    unsigned short* apbuf = (unsigned short*)(xcr + 4194304);   // 2,097,152 fp16

    // dt region (sequential lifetimes, all offsets in f32 units):
    unsigned short* wih    = (unsigned short*)dtr;               // [0,4.19M) in_proj W; dead after gemm
    unsigned short* dth    = (unsigned short*)dtr;               // [0,4.19M) dt fp16; dead after pass3
    unsigned short* oparth = (unsigned short*)dtr;               // [0,4.19M) out partials (after pass3)
    unsigned short* wxh    = (unsigned short*)(dtr + 4194304);   // [4.19M,4.33M) padded Wx
    unsigned short* xparth = (unsigned short*)(dtr + 4325376);   // [4.33M,6.42M) xproj partials
    unsigned short* woh    = (unsigned short*)(dtr + 6422528);   // [6.42M,7.47M) wo fp16
    unsigned short* wdh    = (unsigned short*)(dtr + 7471104);   // [7.47M,7.54M) wd fp16
    unsigned short* dlh    = (unsigned short*)(dtr + 7536640);   // [7.54M,7.67M) dt_low fp16

    // 1) fp16 operands: x, wi, Wx(pad), wd, wo
    cvt_in_k<<<10624, 256, 0, stream>>>(x, wi, wx, wd, wo, xh, wih, wxh, wdh, woh);
    // 2) xz = x @ in_proj_w^T  -> fp16 (M=4096, N=4096, K=1024), 256x128 / 2 blocks/CU
    gemm_inproj<<<512, 512, 0, stream>>>(xh, wih, xzh, 1024, 4096, 16, 1024, 1024);
    // 3) xch = fp16 silu(conv(xs)+b)  (overwrites xh — dead)
    conv_silu_k<<<4096, 256, 0, stream>>>(xzh, cw, cb, xch);
    // 4) x_dbl = xch @ Wx^T, split-K 8x256 -> fp16 partials; reduce -> xdbl f32 + dlh fp16
    gemm_mfma_h<<<256, 256, 0, stream>>>(xch, wxh, xparth, 256, 128, 128, 32, 2048, 4096, 2048,
                                         nullptr, 8, NROWS * 128);
    xproj_reduce_k<<<512, 256, 0, stream>>>(xparth, xdbl, dlh);
    // 5) dt = fp16 softplus(dt_low @ Wd^T + bd)
    gemm_mfma_h<<<512, 256, 0, stream>>>(dlh, wdh, dth, 64, 2048, 2048, 32, 64, 128, 64,
                                         bd, 1, 0);
    // 6) chunked scan (NCH=32, CHL=64, fp16 chunk states); pass3 writes op fp16 dense
    scan_pass1<<<dim3(8, NCH, 2), 256, 0, stream>>>(dth, xch, xdbl, alog, hbuf, apbuf);
    scan_pass2<<<256, 256, 0, stream>>>(hbuf, apbuf);
    scan_pass3<<<dim3(8, NCH, 2), 256, 0, stream>>>(dth, xch, xzh, xdbl, alog, Dp, hbuf, oph);
    // 7) out = op @ out_proj_w^T, split-K 2x1024 -> fp16 partials (dth dead) + reduce
    gemm_mfma_h<<<512, 256, 0, stream>>>(oph, woh, oparth, 1024, 1024, 1024, 32, 2048, 4096, 2048,
                                         nullptr, 2, 4194304);
    out_reduce_k<<<4096, 256, 0, stream>>>(oparth, out);
}

// Round 20
// 183.501 us; speedup vs baseline: 1.0801x; 1.0801x over previous
//
#include <hip/hip_runtime.h>

#define SEQ    2048
#define DIN    2048
#define DMODEL 1024
#define NROWS  4096   // BATCH*SEQ
#define NCH    64     // scan chunks
#define CHL    32     // chunk length

typedef __attribute__((ext_vector_type(8))) _Float16 half8v;
typedef __attribute__((ext_vector_type(8))) unsigned short ushort8v;
typedef __attribute__((ext_vector_type(4))) float f32x4;

__device__ __forceinline__ float sigf(float x) { return 1.0f / (1.0f + __expf(-x)); }
// inline softplus: no libm call (log1pf is a non-inlined OCML slow path — was a 100 µs pathology)
__device__ __forceinline__ float softplusf(float v) {
    return fmaxf(v, 0.f) + __logf(1.f + __expf(-fabsf(v)));
}

__device__ __forceinline__ void gload16(const void* g, const void* l) {
    __builtin_amdgcn_global_load_lds((const __attribute__((address_space(1))) void*)g,
                                     (__attribute__((address_space(3))) void*)l, 16, 0, 0);
}

__device__ __forceinline__ unsigned short f2h(float x) {
    _Float16 h = (_Float16)x;           // v_cvt_f16_f32, RNE
    unsigned short u;
    __builtin_memcpy(&u, &h, 2);
    return u;
}
__device__ __forceinline__ float h2f(unsigned short u) {
    _Float16 h;
    __builtin_memcpy(&h, &u, 2);
    return (float)h;
}

// ---------------- fused fp32 -> fp16 convert: x, wi, Wx(pad 128), wd, wo ----------------
__global__ __launch_bounds__(256) void cvt_in_k(
    const float* __restrict__ x, const float* __restrict__ wi, const float* __restrict__ wx,
    const float* __restrict__ wd, const float* __restrict__ wo,
    unsigned short* __restrict__ xh, unsigned short* __restrict__ wih,
    unsigned short* __restrict__ wxh, unsigned short* __restrict__ wdh,
    unsigned short* __restrict__ woh)
{
    int i = blockIdx.x * 256 + threadIdx.x;    // 2719744 total float4s
    if (i < 1048576) {
        float4 v = ((const float4*)x)[i];
        ushort4 h; h.x = f2h(v.x); h.y = f2h(v.y); h.z = f2h(v.z); h.w = f2h(v.w);
        ((ushort4*)xh)[i] = h;
    } else if (i < 2097152) {
        i -= 1048576;
        float4 v = ((const float4*)wi)[i];
        ushort4 h; h.x = f2h(v.x); h.y = f2h(v.y); h.z = f2h(v.z); h.w = f2h(v.w);
        ((ushort4*)wih)[i] = h;
    } else if (i < 2162688) {
        i -= 2097152;
        int row = i >> 9, q = i & 511;        // [128][512 x float4]
        ushort4 h;
        if (row < 96) {
            float4 v = ((const float4*)wx)[(size_t)row * 512 + q];
            h.x = f2h(v.x); h.y = f2h(v.y); h.z = f2h(v.z); h.w = f2h(v.w);
        } else h = make_ushort4(0, 0, 0, 0);
        ((ushort4*)wxh)[(size_t)row * 512 + q] = h;
    } else if (i < 2195456) {
        i -= 2162688;                          // wd: 2048x64 dense
        float4 v = ((const float4*)wd)[i];
        ushort4 h; h.x = f2h(v.x); h.y = f2h(v.y); h.z = f2h(v.z); h.w = f2h(v.w);
        ((ushort4*)wdh)[i] = h;
    } else {
        i -= 2195456;                          // wo: 1024x2048
        float4 v = ((const float4*)wo)[i];
        ushort4 h; h.x = f2h(v.x); h.y = f2h(v.y); h.z = f2h(v.z); h.w = f2h(v.w);
        ((ushort4*)woh)[i] = h;
    }
}

// ======== in_proj GEMM: 256x128 tile, single-buffer 48 KiB LDS, 512 blocks (2/CU) ======
__global__ __launch_bounds__(512, 4) void gemm_inproj(
    const unsigned short* __restrict__ A, const unsigned short* __restrict__ W,
    unsigned short* __restrict__ C, int K, int N, int mtiles, int lda, int ldw)
{
    __shared__ uint4 ldsu4[3072];          // 48 KiB: A[256][64] @0, B[128][64] @32768
    char* lds = (char*)ldsu4;
    const int tid = threadIdx.x;
    const int w = tid >> 6, lane = tid & 63;

    const int nwg = gridDim.x;
    const int cpx = nwg >> 3;
    const int bid = blockIdx.x;
    const int swz = (bid & 7) * cpx + (bid >> 3);
    const int ntiles = nwg / mtiles;
    const int per = 8 * ntiles;
    const int gid = swz / per;
    const int rem = swz - gid * per;
    const int m0 = (gid * 8 + (rem & 7)) * 256;
    const int n0 = (rem >> 3) * 128;

    const int wr = w >> 2, wc = w & 3;     // wave tile: 128 x 32
    const int lm = lane & 15, lk = lane >> 4;

    f32x4 acc[8][2];
#pragma unroll
    for (int i = 0; i < 8; ++i)
#pragma unroll
        for (int j = 0; j < 2; ++j) { acc[i][j][0]=0.f; acc[i][j][1]=0.f; acc[i][j][2]=0.f; acc[i][j][3]=0.f; }

    const int rsub = w * 8 + (lane >> 3);
    const int xr8  = ((lane & 7) ^ (lane >> 3)) << 3;   // pre-swizzled col chunk
    const unsigned short* gA = A + (size_t)(m0 + rsub) * lda + xr8;
    const unsigned short* gW = W + (size_t)(n0 + rsub) * ldw + xr8;
    const int sdst = w * 1024;                           // + lane*16 appended by HW

    for (int kt = 0; kt < K; kt += 64) {
#pragma unroll
        for (int i = 0; i < 4; ++i)
            gload16(gA + (size_t)i * 64 * lda + kt, lds + i * 8192 + sdst);
#pragma unroll
        for (int i = 0; i < 2; ++i)
            gload16(gW + (size_t)i * 64 * ldw + kt, lds + 32768 + i * 8192 + sdst);
        __syncthreads();
#pragma unroll
        for (int kk = 0; kk < 2; ++kk) {
            half8v b[2];
#pragma unroll
            for (int nb = 0; nb < 2; ++nb) {
                const int br = wc * 32 + nb * 16 + lm;
                b[nb] = *(const half8v*)(lds + 32768 + br * 128 + (((kk * 4 + lk) ^ (br & 7)) << 4));
            }
            __builtin_amdgcn_s_setprio(1);
#pragma unroll
            for (int mb = 0; mb < 8; ++mb) {
                const int ar = wr * 128 + mb * 16 + lm;
                half8v a = *(const half8v*)(lds + ar * 128 + (((kk * 4 + lk) ^ (ar & 7)) << 4));
#pragma unroll
                for (int nb = 0; nb < 2; ++nb)
                    acc[mb][nb] = __builtin_amdgcn_mfma_f32_16x16x32_f16(a, b[nb], acc[mb][nb], 0, 0, 0);
            }
            __builtin_amdgcn_s_setprio(0);
        }
        __syncthreads();
    }

#pragma unroll
    for (int mb = 0; mb < 8; ++mb)
#pragma unroll
        for (int nb = 0; nb < 2; ++nb)
#pragma unroll
            for (int r = 0; r < 4; ++r)
                C[(size_t)(m0 + wr * 128 + mb * 16 + lk * 4 + r) * N + (n0 + wc * 32 + nb * 16 + lm)]
                    = f2h(acc[mb][nb][r]);
}

// ---------------- 128x128 fp16 MFMA GEMM, split-K, fp16 output ----------------
#define A_OFF 0
#define W_OFF 16384

__global__ __launch_bounds__(256) void gemm_mfma_h(
    const unsigned short* __restrict__ A, const unsigned short* __restrict__ W,
    unsigned short* __restrict__ C, int K, int ldc, int nmax, int mtiles,
    int sA1, int sA2, int ldw, const float* __restrict__ bias, int kspl, int cstride)
{
    __shared__ uint4 ldsu4[2048];
    char* lds = (char*)ldsu4;
    const int tid  = threadIdx.x;
    const int w    = tid >> 6, lane = tid & 63;

    const int nwg = gridDim.x;
    const int cpx = nwg >> 3;
    const int bid = blockIdx.x;
    const int swz = (bid & 7) * cpx + (bid >> 3);
    const int nbp = nwg / kspl;
    const int ks  = swz / nbp;
    const int tt  = swz - ks * nbp;
    const int ntiles = nbp / mtiles;
    const int per = 8 * ntiles;
    const int gid = tt / per;
    const int rem = tt - gid * per;
    const int m0 = (gid * 8 + (rem & 7)) * 128;
    const int n0 = (rem >> 3) * 128;
    const int kOff = ks * K;

    const int wr = w >> 1, wc = w & 1;

    f32x4 acc[4][4];
#pragma unroll
    for (int i = 0; i < 4; ++i)
#pragma unroll
        for (int j = 0; j < 4; ++j) { acc[i][j][0]=0.f; acc[i][j][1]=0.f; acc[i][j][2]=0.f; acc[i][j][3]=0.f; }

    const int rloc = w * 32 + (lane >> 3);
    const int xr8  = ((lane & 7) ^ (lane >> 3)) << 3;
    const int rowA = m0 + rloc;
    const unsigned short* gA = A + (size_t)(rowA >> 1) * sA2 + (size_t)(rowA & 1) * sA1 + kOff + xr8;
    const unsigned short* gW = W + (size_t)(n0 + rloc) * ldw + kOff + xr8;

    const int lm  = lane & 15;
    const int lk  = lane >> 4;
    const int lk4 = lk * 4;

    for (int kt = 0; kt < K; kt += 64) {
#pragma unroll
        for (int i = 0; i < 4; ++i) {
            const int rb = w * 32 + i * 8;
            gload16(gA + (size_t)i * 4 * sA2 + kt, lds + A_OFF + rb * 128);
            gload16(gW + (size_t)i * 8 * ldw + kt, lds + W_OFF + rb * 128);
        }
        __syncthreads();
#pragma unroll
        for (int h = 0; h < 2; ++h) {
            half8v af[4], wf[4];
            const int ch = h * 4 + lk;
#pragma unroll
            for (int t = 0; t < 4; ++t) {
                const int ar = wr * 64 + t * 16 + lm;
                const int wrw = wc * 64 + t * 16 + lm;
                af[t] = *(const half8v*)(lds + A_OFF + ar * 128 + ((ch ^ (ar & 7)) << 4));
                wf[t] = *(const half8v*)(lds + W_OFF + wrw * 128 + ((ch ^ (wrw & 7)) << 4));
            }
#pragma unroll
            for (int i = 0; i < 4; ++i)
#pragma unroll
                for (int j = 0; j < 4; ++j)
                    acc[i][j] = __builtin_amdgcn_mfma_f32_16x16x32_f16(af[i], wf[j], acc[i][j], 0, 0, 0);
        }
        __syncthreads();
    }

    unsigned short* Cp = C + (size_t)ks * cstride;
    if (bias) {
#pragma unroll
        for (int j = 0; j < 4; ++j) {
            const int n = n0 + wc * 64 + j * 16 + lm;
            const float bv = (n < nmax) ? bias[n] : 0.f;
#pragma unroll
            for (int i = 0; i < 4; ++i)
#pragma unroll
                for (int r = 0; r < 4; ++r) {
                    float v = acc[i][j][r] + bv;
                    if (n < nmax)
                        Cp[(size_t)(m0 + wr * 64 + i * 16 + lk4 + r) * ldc + n] = f2h(softplusf(v));
                }
        }
    } else {
#pragma unroll
        for (int i = 0; i < 4; ++i)
#pragma unroll
            for (int j = 0; j < 4; ++j) {
                const int n = n0 + wc * 64 + j * 16 + lm;
                if (n < nmax)
#pragma unroll
                    for (int r = 0; r < 4; ++r)
                        Cp[(size_t)(m0 + wr * 64 + i * 16 + lk4 + r) * ldc + n] = f2h(acc[i][j][r]);
            }
    }
}

// xproj reduce: sum 8 fp16 partials; cols 0..63 -> dlh fp16, cols 64..95 -> xdbl f32
__global__ __launch_bounds__(256) void xproj_reduce_k(
    const unsigned short* __restrict__ part, float* __restrict__ xdbl,
    unsigned short* __restrict__ dlh)
{
    int i = blockIdx.x * 256 + threadIdx.x;   // NROWS*32 quads
    if (i >= NROWS * 32) return;
    int row = i >> 5, q = i & 31;
    float s0 = 0.f, s1 = 0.f, s2 = 0.f, s3 = 0.f;
#pragma unroll
    for (int ks = 0; ks < 8; ++ks) {
        ushort4 v = *(const ushort4*)(part + (size_t)ks * (NROWS * 128) + (size_t)row * 128 + q * 4);
        s0 += h2f(v.x); s1 += h2f(v.y); s2 += h2f(v.z); s3 += h2f(v.w);
    }
    if (q < 16) {
        ushort4 h; h.x = f2h(s0); h.y = f2h(s1); h.z = f2h(s2); h.w = f2h(s3);
        *(ushort4*)(dlh + (size_t)row * 64 + q * 4) = h;
    } else {
        *(float4*)(xdbl + (size_t)row * 96 + q * 4) = make_float4(s0, s1, s2, s3);
    }
}

// out_proj partial reduce: out = p0 + p1 (fp16 partials -> f32 out)
__global__ __launch_bounds__(256) void out_reduce_k(
    const unsigned short* __restrict__ p, float* __restrict__ out)
{
    int i = blockIdx.x * 256 + threadIdx.x;   // 1048576 quads
    ushort4 a = ((const ushort4*)p)[i];
    ushort4 b = ((const ushort4*)(p + 4194304))[i];
    float4 v;
    v.x = h2f(a.x) + h2f(b.x);
    v.y = h2f(a.y) + h2f(b.y);
    v.z = h2f(a.z) + h2f(b.z);
    v.w = h2f(a.w) + h2f(b.w);
    ((float4*)out)[i] = v;
}

// ---------------- causal depthwise conv(4) + bias + SiLU, fp16 in -> fp16 out ----------
__global__ __launch_bounds__(256) void conv_silu_k(
    const unsigned short* __restrict__ xzh, const float* __restrict__ cw,
    const float* __restrict__ cb, unsigned short* __restrict__ xch)
{
    int i = blockIdx.x * 256 + threadIdx.x;   // NROWS*256
    int d8 = (i & 255) << 3;
    int row = i >> 8;
    int l = row & (SEQ - 1);
    const unsigned short* base = xzh + (size_t)row * 4096 + d8;
    ushort8v x0 = *(const ushort8v*)base;
    ushort8v x1 = {}, x2 = {}, x3 = {};
    if (l >= 1) x1 = *(const ushort8v*)(base - 4096);
    if (l >= 2) x2 = *(const ushort8v*)(base - 8192);
    if (l >= 3) x3 = *(const ushort8v*)(base - 12288);
    ushort8v out;
#pragma unroll
    for (int j = 0; j < 8; ++j) {
        float4 wv = *(const float4*)(cw + (size_t)(d8 + j) * 4);
        float a = cb[d8 + j];
        a = fmaf(h2f(x3[j]), wv.x, a);
        a = fmaf(h2f(x2[j]), wv.y, a);
        a = fmaf(h2f(x1[j]), wv.z, a);
        a = fmaf(h2f(x0[j]), wv.w, a);
        out[j] = f2h(a * sigf(a));
    }
    *(ushort8v*)(xch + (size_t)row * DIN + d8) = out;
}

// ---------------- chunked selective scan: register-resident 16-state, fp16 states ------
// A[n] = -(n+1) for the given inputs -> dA via power chain (1 exp + 15 muls),
// runtime-checked with 16-exp fallback.
__global__ __launch_bounds__(256) void scan_pass1(
    const unsigned short* __restrict__ dth, const unsigned short* __restrict__ xch,
    const float* __restrict__ xdbl, const float* __restrict__ Alog,
    unsigned short* __restrict__ hbuf, unsigned short* __restrict__ apbuf)
{
    const int b = blockIdx.z, c = blockIdx.y;
    const int d = blockIdx.x * 256 + threadIdx.x;
    float A[16];
#pragma unroll
    for (int q = 0; q < 4; ++q) *(float4*)&A[q * 4] = *(const float4*)&Alog[(size_t)d * 16 + q * 4];
    bool seq = true;
#pragma unroll
    for (int n = 0; n < 16; ++n) {
        A[n] = -__expf(A[n]);
        seq = seq && (fabsf(A[n] + (float)(n + 1)) < 1e-5f * (float)(n + 1));
    }
    float h[16] = {};
    float sumdt = 0.f;
    const int rowbase = b * SEQ + c * CHL;
    int row = rowbase;
    float dtv = h2f(dth[(size_t)row * DIN + d]);
    float xcv = h2f(xch[(size_t)row * DIN + d]);
    if (seq) {
        for (int t = 0; t < CHL; ++t) {
            const int nrow = row + ((t + 1) < CHL ? 1 : 0);
            float dtv2 = h2f(dth[(size_t)nrow * DIN + d]);
            float xcv2 = h2f(xch[(size_t)nrow * DIN + d]);
            const float* xr = xdbl + (size_t)row * 96;
            float u = dtv * xcv;
            sumdt += dtv;
            float r = __expf(-dtv);
            float dA = r;
#pragma unroll
            for (int n = 0; n < 16; ++n) {
                h[n] = fmaf(dA, h[n], u * xr[64 + n]);
                dA *= r;
            }
            dtv = dtv2; xcv = xcv2; row = nrow;
        }
    } else {
        for (int t = 0; t < CHL; ++t) {
            const int nrow = row + ((t + 1) < CHL ? 1 : 0);
            float dtv2 = h2f(dth[(size_t)nrow * DIN + d]);
            float xcv2 = h2f(xch[(size_t)nrow * DIN + d]);
            const float* xr = xdbl + (size_t)row * 96;
            float u = dtv * xcv;
            sumdt += dtv;
#pragma unroll
            for (int n = 0; n < 16; ++n) {
                float dA = __expf(dtv * A[n]);
                h[n] = fmaf(dA, h[n], u * xr[64 + n]);
            }
            dtv = dtv2; xcv = xcv2; row = nrow;
        }
    }
    float ap[16];
    if (seq) {
        float R = __expf(-sumdt);
        float a = R;
#pragma unroll
        for (int n = 0; n < 16; ++n) { ap[n] = a; a *= R; }
    } else {
#pragma unroll
        for (int n = 0; n < 16; ++n) ap[n] = __expf(sumdt * A[n]);
    }
    size_t e = ((size_t)(b * NCH + c) << 15) + (size_t)d * 16;
    ushort8v hv0, hv1, av0, av1;
#pragma unroll
    for (int n = 0; n < 8; ++n) {
        hv0[n] = f2h(h[n]);  hv1[n] = f2h(h[8 + n]);
        av0[n] = f2h(ap[n]); av1[n] = f2h(ap[8 + n]);
    }
    *(ushort8v*)(hbuf + e)      = hv0;
    *(ushort8v*)(hbuf + e + 8)  = hv1;
    *(ushort8v*)(apbuf + e)     = av0;
    *(ushort8v*)(apbuf + e + 8) = av1;
}

__global__ __launch_bounds__(256) void scan_pass2(
    unsigned short* __restrict__ hbuf, const unsigned short* __restrict__ apbuf)
{
    int idx = blockIdx.x * 256 + threadIdx.x;   // 65536
    int b = idx >> 15;
    int dn = idx & 32767;
    float carry = 0.f;
    for (int c = 0; c < NCH; ++c) {
        size_t e = ((size_t)(b * NCH + c) << 15) + dn;
        float hl = h2f(hbuf[e]);
        float ap = h2f(apbuf[e]);
        hbuf[e] = f2h(carry);
        carry = fmaf(ap, carry, hl);
    }
}

// pass 3: re-scan from h_in (fp16); fused epilogue writes op fp16 (dense [4096][2048])
__global__ __launch_bounds__(256) void scan_pass3(
    const unsigned short* __restrict__ dth, const unsigned short* __restrict__ xch,
    const unsigned short* __restrict__ xzh, const float* __restrict__ xdbl,
    const float* __restrict__ Alog, const float* __restrict__ Dp,
    const unsigned short* __restrict__ hbuf, unsigned short* __restrict__ oph)
{
    const int b = blockIdx.z, c = blockIdx.y;
    const int d = blockIdx.x * 256 + threadIdx.x;
    float A[16];
#pragma unroll
    for (int q = 0; q < 4; ++q) *(float4*)&A[q * 4] = *(const float4*)&Alog[(size_t)d * 16 + q * 4];
    bool seq = true;
#pragma unroll
    for (int n = 0; n < 16; ++n) {
        A[n] = -__expf(A[n]);
        seq = seq && (fabsf(A[n] + (float)(n + 1)) < 1e-5f * (float)(n + 1));
    }
    float h[16];
    size_t e = ((size_t)(b * NCH + c) << 15) + (size_t)d * 16;
    {
        ushort8v hv0 = *(const ushort8v*)(hbuf + e);
        ushort8v hv1 = *(const ushort8v*)(hbuf + e + 8);
#pragma unroll
        for (int n = 0; n < 8; ++n) { h[n] = h2f(hv0[n]); h[8 + n] = h2f(hv1[n]); }
    }
    const float Dd = Dp[d];
    const int rowbase = b * SEQ + c * CHL;
    int row = rowbase;
    float dtv = h2f(dth[(size_t)row * DIN + d]);
    float xcv = h2f(xch[(size_t)row * DIN + d]);
    float zv  = h2f(xzh[(size_t)row * 4096 + DIN + d]);
    if (seq) {
        for (int t = 0; t < CHL; ++t) {
            const int nrow = row + ((t + 1) < CHL ? 1 : 0);
            float dtv2 = h2f(dth[(size_t)nrow * DIN + d]);
            float xcv2 = h2f(xch[(size_t)nrow * DIN + d]);
            float zv2  = h2f(xzh[(size_t)nrow * 4096 + DIN + d]);
            const float* xr = xdbl + (size_t)row * 96;
            float u = dtv * xcv;
            float r = __expf(-dtv);
            float dA = r;
            float y = 0.f;
#pragma unroll
            for (int n = 0; n < 16; ++n) {
                h[n] = fmaf(dA, h[n], u * xr[64 + n]);
                y = fmaf(h[n], xr[80 + n], y);
                dA *= r;
            }
            float val = (y + xcv * Dd) * zv * sigf(zv);
            oph[(size_t)row * DIN + d] = f2h(val);
            dtv = dtv2; xcv = xcv2; zv = zv2; row = nrow;
        }
    } else {
        for (int t = 0; t < CHL; ++t) {
            const int nrow = row + ((t + 1) < CHL ? 1 : 0);
            float dtv2 = h2f(dth[(size_t)nrow * DIN + d]);
            float xcv2 = h2f(xch[(size_t)nrow * DIN + d]);
            float zv2  = h2f(xzh[(size_t)nrow * 4096 + DIN + d]);
            const float* xr = xdbl + (size_t)row * 96;
            float u = dtv * xcv;
            float y = 0.f;
#pragma unroll
            for (int n = 0; n < 16; ++n) {
                float dA = __expf(dtv * A[n]);
                h[n] = fmaf(dA, h[n], u * xr[64 + n]);
                y = fmaf(h[n], xr[80 + n], y);
            }
            float val = (y + xcv * Dd) * zv * sigf(zv);
            oph[(size_t)row * DIN + d] = f2h(val);
            dtv = dtv2; xcv = xcv2; zv = zv2; row = nrow;
        }
    }
}

extern "C" void kernel_launch(void* const* d_in, const int* in_sizes, int n_in,
                              void* d_out, int out_size, void* d_ws, size_t ws_size,
                              hipStream_t stream)
{
    const float* x    = (const float*)d_in[0];
    const float* wi   = (const float*)d_in[1];
    const float* cw   = (const float*)d_in[2];
    const float* cb   = (const float*)d_in[3];
    const float* wx   = (const float*)d_in[4];
    const float* wd   = (const float*)d_in[5];
    const float* bd   = (const float*)d_in[6];
    const float* alog = (const float*)d_in[7];
    const float* Dp   = (const float*)d_in[8];
    const float* wo   = (const float*)d_in[9];
    float* out = (float*)d_out;

    float* wsf  = (float*)d_ws;
    float* xzr  = wsf;                          // region 16,777,216 f32
    float* xcr  = wsf + 16777216;               // region  8,388,608 f32
    float* xdbl = wsf + 25165824;               // [4096][96] f32
    float* dtr  = wsf + 25559040;               // region  8,388,608 f32

    // xz region: fp16 xz [4096][4096] in first half; oph + hbuf in the second half
    unsigned short* xzh = (unsigned short*)xzr;
    float* scr = xzr + 8388608;
    unsigned short* oph  = (unsigned short*)scr;                // [4096][2048] fp16
    unsigned short* hbuf = (unsigned short*)(scr + 4194304);    // 4,194,304 fp16 (NCH=64)

    // xc region: xch fp16 first half; apbuf above it
    unsigned short* xh    = (unsigned short*)xcr;               // in_proj A; dead after gemm
    unsigned short* xch   = (unsigned short*)xcr;               // conv output (overwrites xh)
    unsigned short* apbuf = (unsigned short*)(xcr + 4194304);   // 4,194,304 fp16 (NCH=64)

    // dt region (sequential lifetimes, all offsets in f32 units):
    unsigned short* wih    = (unsigned short*)dtr;               // [0,4.19M) in_proj W; dead after gemm
    unsigned short* dth    = (unsigned short*)dtr;               // [0,4.19M) dt fp16; dead after pass3
    unsigned short* oparth = (unsigned short*)dtr;               // [0,4.19M) out partials (after pass3)
    unsigned short* wxh    = (unsigned short*)(dtr + 4194304);   // [4.19M,4.33M) padded Wx
    unsigned short* xparth = (unsigned short*)(dtr + 4325376);   // [4.33M,6.42M) xproj partials
    unsigned short* woh    = (unsigned short*)(dtr + 6422528);   // [6.42M,7.47M) wo fp16
    unsigned short* wdh    = (unsigned short*)(dtr + 7471104);   // [7.47M,7.54M) wd fp16
    unsigned short* dlh    = (unsigned short*)(dtr + 7536640);   // [7.54M,7.67M) dt_low fp16

    // 1) fp16 operands: x, wi, Wx(pad), wd, wo
    cvt_in_k<<<10624, 256, 0, stream>>>(x, wi, wx, wd, wo, xh, wih, wxh, wdh, woh);
    // 2) xz = x @ in_proj_w^T  -> fp16 (M=4096, N=4096, K=1024), 256x128 / 2 blocks/CU
    gemm_inproj<<<512, 512, 0, stream>>>(xh, wih, xzh, 1024, 4096, 16, 1024, 1024);
    // 3) xch = fp16 silu(conv(xs)+b)  (overwrites xh — dead)
    conv_silu_k<<<4096, 256, 0, stream>>>(xzh, cw, cb, xch);
    // 4) x_dbl = xch @ Wx^T, split-K 8x256 -> fp16 partials; reduce -> xdbl f32 + dlh fp16
    gemm_mfma_h<<<256, 256, 0, stream>>>(xch, wxh, xparth, 256, 128, 128, 32, 2048, 4096, 2048,
                                         nullptr, 8, NROWS * 128);
    xproj_reduce_k<<<512, 256, 0, stream>>>(xparth, xdbl, dlh);
    // 5) dt = fp16 softplus(dt_low @ Wd^T + bd)
    gemm_mfma_h<<<512, 256, 0, stream>>>(dlh, wdh, dth, 64, 2048, 2048, 32, 64, 128, 64,
                                         bd, 1, 0);
    // 6) chunked scan (NCH=64, CHL=32, fp16 chunk states); pass3 writes op fp16 dense
    scan_pass1<<<dim3(8, NCH, 2), 256, 0, stream>>>(dth, xch, xdbl, alog, hbuf, apbuf);
    scan_pass2<<<256, 256, 0, stream>>>(hbuf, apbuf);
    scan_pass3<<<dim3(8, NCH, 2), 256, 0, stream>>>(dth, xch, xzh, xdbl, alog, Dp, hbuf, oph);
    // 7) out = op @ out_proj_w^T, split-K 2x1024 -> fp16 partials (dth dead) + reduce
    gemm_mfma_h<<<512, 256, 0, stream>>>(oph, woh, oparth, 1024, 1024, 1024, 32, 2048, 4096, 2048,
                                         nullptr, 2, 4194304);
    out_reduce_k<<<4096, 256, 0, stream>>>(oparth, out);
}

// Round 21
// 182.048 us; speedup vs baseline: 1.0887x; 1.0080x over previous
//
#include <hip/hip_runtime.h>

#define SEQ    2048
#define DIN    2048
#define DMODEL 1024
#define NROWS  4096   // BATCH*SEQ
#define NCH    64     // scan chunks
#define CHL    32     // chunk length

typedef __attribute__((ext_vector_type(8))) _Float16 half8v;
typedef __attribute__((ext_vector_type(8))) unsigned short ushort8v;
typedef __attribute__((ext_vector_type(4))) float f32x4;

__device__ __forceinline__ float sigf(float x) { return 1.0f / (1.0f + __expf(-x)); }
// inline softplus: no libm call (log1pf is a non-inlined OCML slow path — was a 100 µs pathology)
__device__ __forceinline__ float softplusf(float v) {
    return fmaxf(v, 0.f) + __logf(1.f + __expf(-fabsf(v)));
}

__device__ __forceinline__ void gload16(const void* g, const void* l) {
    __builtin_amdgcn_global_load_lds((const __attribute__((address_space(1))) void*)g,
                                     (__attribute__((address_space(3))) void*)l, 16, 0, 0);
}

__device__ __forceinline__ unsigned short f2h(float x) {
    _Float16 h = (_Float16)x;           // v_cvt_f16_f32, RNE
    unsigned short u;
    __builtin_memcpy(&u, &h, 2);
    return u;
}
__device__ __forceinline__ float h2f(unsigned short u) {
    _Float16 h;
    __builtin_memcpy(&h, &u, 2);
    return (float)h;
}

// ---------------- fused fp32 -> fp16 convert: x, wi, Wx(pad 128), wd, wo ----------------
__global__ __launch_bounds__(256) void cvt_in_k(
    const float* __restrict__ x, const float* __restrict__ wi, const float* __restrict__ wx,
    const float* __restrict__ wd, const float* __restrict__ wo,
    unsigned short* __restrict__ xh, unsigned short* __restrict__ wih,
    unsigned short* __restrict__ wxh, unsigned short* __restrict__ wdh,
    unsigned short* __restrict__ woh)
{
    int i = blockIdx.x * 256 + threadIdx.x;    // 2719744 total float4s
    if (i < 1048576) {
        float4 v = ((const float4*)x)[i];
        ushort4 h; h.x = f2h(v.x); h.y = f2h(v.y); h.z = f2h(v.z); h.w = f2h(v.w);
        ((ushort4*)xh)[i] = h;
    } else if (i < 2097152) {
        i -= 1048576;
        float4 v = ((const float4*)wi)[i];
        ushort4 h; h.x = f2h(v.x); h.y = f2h(v.y); h.z = f2h(v.z); h.w = f2h(v.w);
        ((ushort4*)wih)[i] = h;
    } else if (i < 2162688) {
        i -= 2097152;
        int row = i >> 9, q = i & 511;        // [128][512 x float4]
        ushort4 h;
        if (row < 96) {
            float4 v = ((const float4*)wx)[(size_t)row * 512 + q];
            h.x = f2h(v.x); h.y = f2h(v.y); h.z = f2h(v.z); h.w = f2h(v.w);
        } else h = make_ushort4(0, 0, 0, 0);
        ((ushort4*)wxh)[(size_t)row * 512 + q] = h;
    } else if (i < 2195456) {
        i -= 2162688;                          // wd: 2048x64 dense
        float4 v = ((const float4*)wd)[i];
        ushort4 h; h.x = f2h(v.x); h.y = f2h(v.y); h.z = f2h(v.z); h.w = f2h(v.w);
        ((ushort4*)wdh)[i] = h;
    } else {
        i -= 2195456;                          // wo: 1024x2048
        float4 v = ((const float4*)wo)[i];
        ushort4 h; h.x = f2h(v.x); h.y = f2h(v.y); h.z = f2h(v.z); h.w = f2h(v.w);
        ((ushort4*)woh)[i] = h;
    }
}

// ======== in_proj GEMM: 256x128 tile, single-buffer 48 KiB LDS, 512 blocks (2/CU) ======
__global__ __launch_bounds__(512, 4) void gemm_inproj(
    const unsigned short* __restrict__ A, const unsigned short* __restrict__ W,
    unsigned short* __restrict__ C, int K, int N, int mtiles, int lda, int ldw)
{
    __shared__ uint4 ldsu4[3072];          // 48 KiB: A[256][64] @0, B[128][64] @32768
    char* lds = (char*)ldsu4;
    const int tid = threadIdx.x;
    const int w = tid >> 6, lane = tid & 63;

    const int nwg = gridDim.x;
    const int cpx = nwg >> 3;
    const int bid = blockIdx.x;
    const int swz = (bid & 7) * cpx + (bid >> 3);
    const int ntiles = nwg / mtiles;
    const int per = 8 * ntiles;
    const int gid = swz / per;
    const int rem = swz - gid * per;
    const int m0 = (gid * 8 + (rem & 7)) * 256;
    const int n0 = (rem >> 3) * 128;

    const int wr = w >> 2, wc = w & 3;     // wave tile: 128 x 32
    const int lm = lane & 15, lk = lane >> 4;

    f32x4 acc[8][2];
#pragma unroll
    for (int i = 0; i < 8; ++i)
#pragma unroll
        for (int j = 0; j < 2; ++j) { acc[i][j][0]=0.f; acc[i][j][1]=0.f; acc[i][j][2]=0.f; acc[i][j][3]=0.f; }

    const int rsub = w * 8 + (lane >> 3);
    const int xr8  = ((lane & 7) ^ (lane >> 3)) << 3;   // pre-swizzled col chunk
    const unsigned short* gA = A + (size_t)(m0 + rsub) * lda + xr8;
    const unsigned short* gW = W + (size_t)(n0 + rsub) * ldw + xr8;
    const int sdst = w * 1024;                           // + lane*16 appended by HW

    for (int kt = 0; kt < K; kt += 64) {
#pragma unroll
        for (int i = 0; i < 4; ++i)
            gload16(gA + (size_t)i * 64 * lda + kt, lds + i * 8192 + sdst);
#pragma unroll
        for (int i = 0; i < 2; ++i)
            gload16(gW + (size_t)i * 64 * ldw + kt, lds + 32768 + i * 8192 + sdst);
        __syncthreads();
#pragma unroll
        for (int kk = 0; kk < 2; ++kk) {
            half8v b[2];
#pragma unroll
            for (int nb = 0; nb < 2; ++nb) {
                const int br = wc * 32 + nb * 16 + lm;
                b[nb] = *(const half8v*)(lds + 32768 + br * 128 + (((kk * 4 + lk) ^ (br & 7)) << 4));
            }
            __builtin_amdgcn_s_setprio(1);
#pragma unroll
            for (int mb = 0; mb < 8; ++mb) {
                const int ar = wr * 128 + mb * 16 + lm;
                half8v a = *(const half8v*)(lds + ar * 128 + (((kk * 4 + lk) ^ (ar & 7)) << 4));
#pragma unroll
                for (int nb = 0; nb < 2; ++nb)
                    acc[mb][nb] = __builtin_amdgcn_mfma_f32_16x16x32_f16(a, b[nb], acc[mb][nb], 0, 0, 0);
            }
            __builtin_amdgcn_s_setprio(0);
        }
        __syncthreads();
    }

#pragma unroll
    for (int mb = 0; mb < 8; ++mb)
#pragma unroll
        for (int nb = 0; nb < 2; ++nb)
#pragma unroll
            for (int r = 0; r < 4; ++r)
                C[(size_t)(m0 + wr * 128 + mb * 16 + lk * 4 + r) * N + (n0 + wc * 32 + nb * 16 + lm)]
                    = f2h(acc[mb][nb][r]);
}

// ======== out_proj GEMM: 128x64 tile, full K, f32 output (no split-K, no reduce) ========
// M=4096, N=1024, K=2048 -> grid 32x16 = 512 blocks, 24 KiB LDS, up to 4 blocks/CU.
__global__ __launch_bounds__(256, 4) void gemm_out(
    const unsigned short* __restrict__ A, const unsigned short* __restrict__ W,
    float* __restrict__ C, int K, int N, int mtiles, int lda, int ldw)
{
    __shared__ uint4 ldsu4[1536];          // 24 KiB: A[128][64] @0, W[64][64] @16384
    char* lds = (char*)ldsu4;
    const int tid = threadIdx.x;
    const int w = tid >> 6, lane = tid & 63;

    const int nwg = gridDim.x;             // 512
    const int cpx = nwg >> 3;
    const int bid = blockIdx.x;
    const int swz = (bid & 7) * cpx + (bid >> 3);
    const int ntiles = nwg / mtiles;       // 16
    const int per = 8 * ntiles;            // 128
    const int gid = swz / per;
    const int rem = swz - gid * per;
    const int m0 = (gid * 8 + (rem & 7)) * 128;
    const int n0 = (rem >> 3) * 64;

    const int wr = w >> 1, wc = w & 1;     // wave tile: 64 x 32
    const int lm = lane & 15, lk = lane >> 4;

    f32x4 acc[4][2];
#pragma unroll
    for (int i = 0; i < 4; ++i)
#pragma unroll
        for (int j = 0; j < 2; ++j) { acc[i][j][0]=0.f; acc[i][j][1]=0.f; acc[i][j][2]=0.f; acc[i][j][3]=0.f; }

    const int rloc = w * 8 + (lane >> 3);                // 0..31
    const int xr8  = ((lane & 7) ^ (lane >> 3)) << 3;    // pre-swizzled col chunk
    const unsigned short* gA = A + (size_t)(m0 + rloc) * lda + xr8;
    const unsigned short* gW = W + (size_t)(n0 + rloc) * ldw + xr8;
    const int sdst = w * 1024;                            // + lane*16 appended by HW

    for (int kt = 0; kt < K; kt += 64) {
#pragma unroll
        for (int i = 0; i < 4; ++i)                       // A: 128 rows
            gload16(gA + (size_t)i * 32 * lda + kt, lds + i * 4096 + sdst);
#pragma unroll
        for (int i = 0; i < 2; ++i)                       // W: 64 rows
            gload16(gW + (size_t)i * 32 * ldw + kt, lds + 16384 + i * 4096 + sdst);
        __syncthreads();
#pragma unroll
        for (int kk = 0; kk < 2; ++kk) {
            half8v b[2];
#pragma unroll
            for (int nb = 0; nb < 2; ++nb) {
                const int br = wc * 32 + nb * 16 + lm;
                b[nb] = *(const half8v*)(lds + 16384 + br * 128 + (((kk * 4 + lk) ^ (br & 7)) << 4));
            }
            __builtin_amdgcn_s_setprio(1);
#pragma unroll
            for (int mb = 0; mb < 4; ++mb) {
                const int ar = wr * 64 + mb * 16 + lm;
                half8v a = *(const half8v*)(lds + ar * 128 + (((kk * 4 + lk) ^ (ar & 7)) << 4));
#pragma unroll
                for (int nb = 0; nb < 2; ++nb)
                    acc[mb][nb] = __builtin_amdgcn_mfma_f32_16x16x32_f16(a, b[nb], acc[mb][nb], 0, 0, 0);
            }
            __builtin_amdgcn_s_setprio(0);
        }
        __syncthreads();
    }

#pragma unroll
    for (int mb = 0; mb < 4; ++mb)
#pragma unroll
        for (int nb = 0; nb < 2; ++nb)
#pragma unroll
            for (int r = 0; r < 4; ++r)
                C[(size_t)(m0 + wr * 64 + mb * 16 + lk * 4 + r) * N + (n0 + wc * 32 + nb * 16 + lm)]
                    = acc[mb][nb][r];
}

// ---------------- 128x128 fp16 MFMA GEMM, split-K, fp16 output (xproj / dtproj) --------
#define A_OFF 0
#define W_OFF 16384

__global__ __launch_bounds__(256) void gemm_mfma_h(
    const unsigned short* __restrict__ A, const unsigned short* __restrict__ W,
    unsigned short* __restrict__ C, int K, int ldc, int nmax, int mtiles,
    int sA1, int sA2, int ldw, const float* __restrict__ bias, int kspl, int cstride)
{
    __shared__ uint4 ldsu4[2048];
    char* lds = (char*)ldsu4;
    const int tid  = threadIdx.x;
    const int w    = tid >> 6, lane = tid & 63;

    const int nwg = gridDim.x;
    const int cpx = nwg >> 3;
    const int bid = blockIdx.x;
    const int swz = (bid & 7) * cpx + (bid >> 3);
    const int nbp = nwg / kspl;
    const int ks  = swz / nbp;
    const int tt  = swz - ks * nbp;
    const int ntiles = nbp / mtiles;
    const int per = 8 * ntiles;
    const int gid = tt / per;
    const int rem = tt - gid * per;
    const int m0 = (gid * 8 + (rem & 7)) * 128;
    const int n0 = (rem >> 3) * 128;
    const int kOff = ks * K;

    const int wr = w >> 1, wc = w & 1;

    f32x4 acc[4][4];
#pragma unroll
    for (int i = 0; i < 4; ++i)
#pragma unroll
        for (int j = 0; j < 4; ++j) { acc[i][j][0]=0.f; acc[i][j][1]=0.f; acc[i][j][2]=0.f; acc[i][j][3]=0.f; }

    const int rloc = w * 32 + (lane >> 3);
    const int xr8  = ((lane & 7) ^ (lane >> 3)) << 3;
    const int rowA = m0 + rloc;
    const unsigned short* gA = A + (size_t)(rowA >> 1) * sA2 + (size_t)(rowA & 1) * sA1 + kOff + xr8;
    const unsigned short* gW = W + (size_t)(n0 + rloc) * ldw + kOff + xr8;

    const int lm  = lane & 15;
    const int lk  = lane >> 4;
    const int lk4 = lk * 4;

    for (int kt = 0; kt < K; kt += 64) {
#pragma unroll
        for (int i = 0; i < 4; ++i) {
            const int rb = w * 32 + i * 8;
            gload16(gA + (size_t)i * 4 * sA2 + kt, lds + A_OFF + rb * 128);
            gload16(gW + (size_t)i * 8 * ldw + kt, lds + W_OFF + rb * 128);
        }
        __syncthreads();
#pragma unroll
        for (int h = 0; h < 2; ++h) {
            half8v af[4], wf[4];
            const int ch = h * 4 + lk;
#pragma unroll
            for (int t = 0; t < 4; ++t) {
                const int ar = wr * 64 + t * 16 + lm;
                const int wrw = wc * 64 + t * 16 + lm;
                af[t] = *(const half8v*)(lds + A_OFF + ar * 128 + ((ch ^ (ar & 7)) << 4));
                wf[t] = *(const half8v*)(lds + W_OFF + wrw * 128 + ((ch ^ (wrw & 7)) << 4));
            }
#pragma unroll
            for (int i = 0; i < 4; ++i)
#pragma unroll
                for (int j = 0; j < 4; ++j)
                    acc[i][j] = __builtin_amdgcn_mfma_f32_16x16x32_f16(af[i], wf[j], acc[i][j], 0, 0, 0);
        }
        __syncthreads();
    }

    unsigned short* Cp = C + (size_t)ks * cstride;
    if (bias) {
#pragma unroll
        for (int j = 0; j < 4; ++j) {
            const int n = n0 + wc * 64 + j * 16 + lm;
            const float bv = (n < nmax) ? bias[n] : 0.f;
#pragma unroll
            for (int i = 0; i < 4; ++i)
#pragma unroll
                for (int r = 0; r < 4; ++r) {
                    float v = acc[i][j][r] + bv;
                    if (n < nmax)
                        Cp[(size_t)(m0 + wr * 64 + i * 16 + lk4 + r) * ldc + n] = f2h(softplusf(v));
                }
        }
    } else {
#pragma unroll
        for (int i = 0; i < 4; ++i)
#pragma unroll
            for (int j = 0; j < 4; ++j) {
                const int n = n0 + wc * 64 + j * 16 + lm;
                if (n < nmax)
#pragma unroll
                    for (int r = 0; r < 4; ++r)
                        Cp[(size_t)(m0 + wr * 64 + i * 16 + lk4 + r) * ldc + n] = f2h(acc[i][j][r]);
            }
    }
}

// xproj reduce: sum 8 fp16 partials; cols 0..63 -> dlh fp16, cols 64..95 -> xdbl f32
__global__ __launch_bounds__(256) void xproj_reduce_k(
    const unsigned short* __restrict__ part, float* __restrict__ xdbl,
    unsigned short* __restrict__ dlh)
{
    int i = blockIdx.x * 256 + threadIdx.x;   // NROWS*32 quads
    if (i >= NROWS * 32) return;
    int row = i >> 5, q = i & 31;
    float s0 = 0.f, s1 = 0.f, s2 = 0.f, s3 = 0.f;
#pragma unroll
    for (int ks = 0; ks < 8; ++ks) {
        ushort4 v = *(const ushort4*)(part + (size_t)ks * (NROWS * 128) + (size_t)row * 128 + q * 4);
        s0 += h2f(v.x); s1 += h2f(v.y); s2 += h2f(v.z); s3 += h2f(v.w);
    }
    if (q < 16) {
        ushort4 h; h.x = f2h(s0); h.y = f2h(s1); h.z = f2h(s2); h.w = f2h(s3);
        *(ushort4*)(dlh + (size_t)row * 64 + q * 4) = h;
    } else {
        *(float4*)(xdbl + (size_t)row * 96 + q * 4) = make_float4(s0, s1, s2, s3);
    }
}

// ---------------- causal depthwise conv(4) + bias + SiLU, fp16 in -> fp16 out ----------
__global__ __launch_bounds__(256) void conv_silu_k(
    const unsigned short* __restrict__ xzh, const float* __restrict__ cw,
    const float* __restrict__ cb, unsigned short* __restrict__ xch)
{
    int i = blockIdx.x * 256 + threadIdx.x;   // NROWS*256
    int d8 = (i & 255) << 3;
    int row = i >> 8;
    int l = row & (SEQ - 1);
    const unsigned short* base = xzh + (size_t)row * 4096 + d8;
    ushort8v x0 = *(const ushort8v*)base;
    ushort8v x1 = {}, x2 = {}, x3 = {};
    if (l >= 1) x1 = *(const ushort8v*)(base - 4096);
    if (l >= 2) x2 = *(const ushort8v*)(base - 8192);
    if (l >= 3) x3 = *(const ushort8v*)(base - 12288);
    ushort8v out;
#pragma unroll
    for (int j = 0; j < 8; ++j) {
        float4 wv = *(const float4*)(cw + (size_t)(d8 + j) * 4);
        float a = cb[d8 + j];
        a = fmaf(h2f(x3[j]), wv.x, a);
        a = fmaf(h2f(x2[j]), wv.y, a);
        a = fmaf(h2f(x1[j]), wv.z, a);
        a = fmaf(h2f(x0[j]), wv.w, a);
        out[j] = f2h(a * sigf(a));
    }
    *(ushort8v*)(xch + (size_t)row * DIN + d8) = out;
}

// ---------------- chunked selective scan: register-resident 16-state, fp16 states ------
// A[n] = -(n+1) for the given inputs -> dA via power chain (1 exp + 15 muls),
// runtime-checked with 16-exp fallback.
__global__ __launch_bounds__(256) void scan_pass1(
    const unsigned short* __restrict__ dth, const unsigned short* __restrict__ xch,
    const float* __restrict__ xdbl, const float* __restrict__ Alog,
    unsigned short* __restrict__ hbuf, unsigned short* __restrict__ apbuf)
{
    const int b = blockIdx.z, c = blockIdx.y;
    const int d = blockIdx.x * 256 + threadIdx.x;
    float A[16];
#pragma unroll
    for (int q = 0; q < 4; ++q) *(float4*)&A[q * 4] = *(const float4*)&Alog[(size_t)d * 16 + q * 4];
    bool seq = true;
#pragma unroll
    for (int n = 0; n < 16; ++n) {
        A[n] = -__expf(A[n]);
        seq = seq && (fabsf(A[n] + (float)(n + 1)) < 1e-5f * (float)(n + 1));
    }
    float h[16] = {};
    float sumdt = 0.f;
    const int rowbase = b * SEQ + c * CHL;
    int row = rowbase;
    float dtv = h2f(dth[(size_t)row * DIN + d]);
    float xcv = h2f(xch[(size_t)row * DIN + d]);
    if (seq) {
        for (int t = 0; t < CHL; ++t) {
            const int nrow = row + ((t + 1) < CHL ? 1 : 0);
            float dtv2 = h2f(dth[(size_t)nrow * DIN + d]);
            float xcv2 = h2f(xch[(size_t)nrow * DIN + d]);
            const float* xr = xdbl + (size_t)row * 96;
            float u = dtv * xcv;
            sumdt += dtv;
            float r = __expf(-dtv);
            float dA = r;
#pragma unroll
            for (int n = 0; n < 16; ++n) {
                h[n] = fmaf(dA, h[n], u * xr[64 + n]);
                dA *= r;
            }
            dtv = dtv2; xcv = xcv2; row = nrow;
        }
    } else {
        for (int t = 0; t < CHL; ++t) {
            const int nrow = row + ((t + 1) < CHL ? 1 : 0);
            float dtv2 = h2f(dth[(size_t)nrow * DIN + d]);
            float xcv2 = h2f(xch[(size_t)nrow * DIN + d]);
            const float* xr = xdbl + (size_t)row * 96;
            float u = dtv * xcv;
            sumdt += dtv;
#pragma unroll
            for (int n = 0; n < 16; ++n) {
                float dA = __expf(dtv * A[n]);
                h[n] = fmaf(dA, h[n], u * xr[64 + n]);
            }
            dtv = dtv2; xcv = xcv2; row = nrow;
        }
    }
    float ap[16];
    if (seq) {
        float R = __expf(-sumdt);
        float a = R;
#pragma unroll
        for (int n = 0; n < 16; ++n) { ap[n] = a; a *= R; }
    } else {
#pragma unroll
        for (int n = 0; n < 16; ++n) ap[n] = __expf(sumdt * A[n]);
    }
    size_t e = ((size_t)(b * NCH + c) << 15) + (size_t)d * 16;
    ushort8v hv0, hv1, av0, av1;
#pragma unroll
    for (int n = 0; n < 8; ++n) {
        hv0[n] = f2h(h[n]);  hv1[n] = f2h(h[8 + n]);
        av0[n] = f2h(ap[n]); av1[n] = f2h(ap[8 + n]);
    }
    *(ushort8v*)(hbuf + e)      = hv0;
    *(ushort8v*)(hbuf + e + 8)  = hv1;
    *(ushort8v*)(apbuf + e)     = av0;
    *(ushort8v*)(apbuf + e + 8) = av1;
}

__global__ __launch_bounds__(256) void scan_pass2(
    unsigned short* __restrict__ hbuf, const unsigned short* __restrict__ apbuf)
{
    int idx = blockIdx.x * 256 + threadIdx.x;   // 65536
    int b = idx >> 15;
    int dn = idx & 32767;
    float carry = 0.f;
    for (int c = 0; c < NCH; ++c) {
        size_t e = ((size_t)(b * NCH + c) << 15) + dn;
        float hl = h2f(hbuf[e]);
        float ap = h2f(apbuf[e]);
        hbuf[e] = f2h(carry);
        carry = fmaf(ap, carry, hl);
    }
}

// pass 3: re-scan from h_in (fp16); fused epilogue writes op fp16 (dense [4096][2048])
__global__ __launch_bounds__(256) void scan_pass3(
    const unsigned short* __restrict__ dth, const unsigned short* __restrict__ xch,
    const unsigned short* __restrict__ xzh, const float* __restrict__ xdbl,
    const float* __restrict__ Alog, const float* __restrict__ Dp,
    const unsigned short* __restrict__ hbuf, unsigned short* __restrict__ oph)
{
    const int b = blockIdx.z, c = blockIdx.y;
    const int d = blockIdx.x * 256 + threadIdx.x;
    float A[16];
#pragma unroll
    for (int q = 0; q < 4; ++q) *(float4*)&A[q * 4] = *(const float4*)&Alog[(size_t)d * 16 + q * 4];
    bool seq = true;
#pragma unroll
    for (int n = 0; n < 16; ++n) {
        A[n] = -__expf(A[n]);
        seq = seq && (fabsf(A[n] + (float)(n + 1)) < 1e-5f * (float)(n + 1));
    }
    float h[16];
    size_t e = ((size_t)(b * NCH + c) << 15) + (size_t)d * 16;
    {
        ushort8v hv0 = *(const ushort8v*)(hbuf + e);
        ushort8v hv1 = *(const ushort8v*)(hbuf + e + 8);
#pragma unroll
        for (int n = 0; n < 8; ++n) { h[n] = h2f(hv0[n]); h[8 + n] = h2f(hv1[n]); }
    }
    const float Dd = Dp[d];
    const int rowbase = b * SEQ + c * CHL;
    int row = rowbase;
    float dtv = h2f(dth[(size_t)row * DIN + d]);
    float xcv = h2f(xch[(size_t)row * DIN + d]);
    float zv  = h2f(xzh[(size_t)row * 4096 + DIN + d]);
    if (seq) {
        for (int t = 0; t < CHL; ++t) {
            const int nrow = row + ((t + 1) < CHL ? 1 : 0);
            float dtv2 = h2f(dth[(size_t)nrow * DIN + d]);
            float xcv2 = h2f(xch[(size_t)nrow * DIN + d]);
            float zv2  = h2f(xzh[(size_t)nrow * 4096 + DIN + d]);
            const float* xr = xdbl + (size_t)row * 96;
            float u = dtv * xcv;
            float r = __expf(-dtv);
            float dA = r;
            float y = 0.f;
#pragma unroll
            for (int n = 0; n < 16; ++n) {
                h[n] = fmaf(dA, h[n], u * xr[64 + n]);
                y = fmaf(h[n], xr[80 + n], y);
                dA *= r;
            }
            float val = (y + xcv * Dd) * zv * sigf(zv);
            oph[(size_t)row * DIN + d] = f2h(val);
            dtv = dtv2; xcv = xcv2; zv = zv2; row = nrow;
        }
    } else {
        for (int t = 0; t < CHL; ++t) {
            const int nrow = row + ((t + 1) < CHL ? 1 : 0);
            float dtv2 = h2f(dth[(size_t)nrow * DIN + d]);
            float xcv2 = h2f(xch[(size_t)nrow * DIN + d]);
            float zv2  = h2f(xzh[(size_t)nrow * 4096 + DIN + d]);
            const float* xr = xdbl + (size_t)row * 96;
            float u = dtv * xcv;
            float y = 0.f;
#pragma unroll
            for (int n = 0; n < 16; ++n) {
                float dA = __expf(dtv * A[n]);
                h[n] = fmaf(dA, h[n], u * xr[64 + n]);
                y = fmaf(h[n], xr[80 + n], y);
            }
            float val = (y + xcv * Dd) * zv * sigf(zv);
            oph[(size_t)row * DIN + d] = f2h(val);
            dtv = dtv2; xcv = xcv2; zv = zv2; row = nrow;
        }
    }
}

extern "C" void kernel_launch(void* const* d_in, const int* in_sizes, int n_in,
                              void* d_out, int out_size, void* d_ws, size_t ws_size,
                              hipStream_t stream)
{
    const float* x    = (const float*)d_in[0];
    const float* wi   = (const float*)d_in[1];
    const float* cw   = (const float*)d_in[2];
    const float* cb   = (const float*)d_in[3];
    const float* wx   = (const float*)d_in[4];
    const float* wd   = (const float*)d_in[5];
    const float* bd   = (const float*)d_in[6];
    const float* alog = (const float*)d_in[7];
    const float* Dp   = (const float*)d_in[8];
    const float* wo   = (const float*)d_in[9];
    float* out = (float*)d_out;

    float* wsf  = (float*)d_ws;
    float* xzr  = wsf;                          // region 16,777,216 f32
    float* xcr  = wsf + 16777216;               // region  8,388,608 f32
    float* xdbl = wsf + 25165824;               // [4096][96] f32
    float* dtr  = wsf + 25559040;               // region  8,388,608 f32

    // xz region: fp16 xz [4096][4096] in first half; oph + hbuf in the second half
    unsigned short* xzh = (unsigned short*)xzr;
    float* scr = xzr + 8388608;
    unsigned short* oph  = (unsigned short*)scr;                // [4096][2048] fp16
    unsigned short* hbuf = (unsigned short*)(scr + 4194304);    // 4,194,304 fp16 (NCH=64)

    // xc region: xch fp16 first half; apbuf above it
    unsigned short* xh    = (unsigned short*)xcr;               // in_proj A; dead after gemm
    unsigned short* xch   = (unsigned short*)xcr;               // conv output (overwrites xh)
    unsigned short* apbuf = (unsigned short*)(xcr + 4194304);   // 4,194,304 fp16 (NCH=64)

    // dt region (sequential lifetimes, all offsets in f32 units):
    unsigned short* wih    = (unsigned short*)dtr;               // [0,4.19M) in_proj W; dead after gemm
    unsigned short* dth    = (unsigned short*)dtr;               // [0,4.19M) dt fp16; dead after pass3
    unsigned short* wxh    = (unsigned short*)(dtr + 4194304);   // [4.19M,4.33M) padded Wx
    unsigned short* xparth = (unsigned short*)(dtr + 4325376);   // [4.33M,6.42M) xproj partials
    unsigned short* woh    = (unsigned short*)(dtr + 6422528);   // [6.42M,7.47M) wo fp16
    unsigned short* wdh    = (unsigned short*)(dtr + 7471104);   // [7.47M,7.54M) wd fp16
    unsigned short* dlh    = (unsigned short*)(dtr + 7536640);   // [7.54M,7.67M) dt_low fp16

    // 1) fp16 operands: x, wi, Wx(pad), wd, wo
    cvt_in_k<<<10624, 256, 0, stream>>>(x, wi, wx, wd, wo, xh, wih, wxh, wdh, woh);
    // 2) xz = x @ in_proj_w^T  -> fp16 (M=4096, N=4096, K=1024), 256x128 / 2 blocks/CU
    gemm_inproj<<<512, 512, 0, stream>>>(xh, wih, xzh, 1024, 4096, 16, 1024, 1024);
    // 3) xch = fp16 silu(conv(xs)+b)  (overwrites xh — dead)
    conv_silu_k<<<4096, 256, 0, stream>>>(xzh, cw, cb, xch);
    // 4) x_dbl = xch @ Wx^T, split-K 8x256 -> fp16 partials; reduce -> xdbl f32 + dlh fp16
    gemm_mfma_h<<<256, 256, 0, stream>>>(xch, wxh, xparth, 256, 128, 128, 32, 2048, 4096, 2048,
                                         nullptr, 8, NROWS * 128);
    xproj_reduce_k<<<512, 256, 0, stream>>>(xparth, xdbl, dlh);
    // 5) dt = fp16 softplus(dt_low @ Wd^T + bd)
    gemm_mfma_h<<<512, 256, 0, stream>>>(dlh, wdh, dth, 64, 2048, 2048, 32, 64, 128, 64,
                                         bd, 1, 0);
    // 6) chunked scan (NCH=64, CHL=32, fp16 chunk states); pass3 writes op fp16 dense
    scan_pass1<<<dim3(8, NCH, 2), 256, 0, stream>>>(dth, xch, xdbl, alog, hbuf, apbuf);
    scan_pass2<<<256, 256, 0, stream>>>(hbuf, apbuf);
    scan_pass3<<<dim3(8, NCH, 2), 256, 0, stream>>>(dth, xch, xzh, xdbl, alog, Dp, hbuf, oph);
    // 7) out = op @ out_proj_w^T (M=4096, N=1024, K=2048), 128x64 tiles, f32 out direct
    gemm_out<<<512, 256, 0, stream>>>(oph, woh, out, 2048, 1024, 32, 2048, 2048);
}

// Round 22
// 182.027 us; speedup vs baseline: 1.0889x; 1.0001x over previous
//
#include <hip/hip_runtime.h>

#define SEQ    2048
#define DIN    2048
#define DMODEL 1024
#define NROWS  4096   // BATCH*SEQ
#define NCH    64     // scan chunks
#define CHL    32     // chunk length

typedef __attribute__((ext_vector_type(8))) _Float16 half8v;
typedef __attribute__((ext_vector_type(8))) unsigned short ushort8v;
typedef __attribute__((ext_vector_type(4))) float f32x4;

__device__ __forceinline__ float sigf(float x) { return 1.0f / (1.0f + __expf(-x)); }
// inline softplus: no libm call (log1pf is a non-inlined OCML slow path — was a 100 µs pathology)
__device__ __forceinline__ float softplusf(float v) {
    return fmaxf(v, 0.f) + __logf(1.f + __expf(-fabsf(v)));
}

__device__ __forceinline__ void gload16(const void* g, const void* l) {
    __builtin_amdgcn_global_load_lds((const __attribute__((address_space(1))) void*)g,
                                     (__attribute__((address_space(3))) void*)l, 16, 0, 0);
}

__device__ __forceinline__ unsigned short f2h(float x) {
    _Float16 h = (_Float16)x;           // v_cvt_f16_f32, RNE
    unsigned short u;
    __builtin_memcpy(&u, &h, 2);
    return u;
}
__device__ __forceinline__ float h2f(unsigned short u) {
    _Float16 h;
    __builtin_memcpy(&h, &u, 2);
    return (float)h;
}

// ---------------- fused fp32 -> fp16 convert: x, wi, Wx(pad 128), wd, wo ----------------
__global__ __launch_bounds__(256) void cvt_in_k(
    const float* __restrict__ x, const float* __restrict__ wi, const float* __restrict__ wx,
    const float* __restrict__ wd, const float* __restrict__ wo,
    unsigned short* __restrict__ xh, unsigned short* __restrict__ wih,
    unsigned short* __restrict__ wxh, unsigned short* __restrict__ wdh,
    unsigned short* __restrict__ woh)
{
    int i = blockIdx.x * 256 + threadIdx.x;    // 2719744 total float4s
    if (i < 1048576) {
        float4 v = ((const float4*)x)[i];
        ushort4 h; h.x = f2h(v.x); h.y = f2h(v.y); h.z = f2h(v.z); h.w = f2h(v.w);
        ((ushort4*)xh)[i] = h;
    } else if (i < 2097152) {
        i -= 1048576;
        float4 v = ((const float4*)wi)[i];
        ushort4 h; h.x = f2h(v.x); h.y = f2h(v.y); h.z = f2h(v.z); h.w = f2h(v.w);
        ((ushort4*)wih)[i] = h;
    } else if (i < 2162688) {
        i -= 2097152;
        int row = i >> 9, q = i & 511;        // [128][512 x float4]
        ushort4 h;
        if (row < 96) {
            float4 v = ((const float4*)wx)[(size_t)row * 512 + q];
            h.x = f2h(v.x); h.y = f2h(v.y); h.z = f2h(v.z); h.w = f2h(v.w);
        } else h = make_ushort4(0, 0, 0, 0);
        ((ushort4*)wxh)[(size_t)row * 512 + q] = h;
    } else if (i < 2195456) {
        i -= 2162688;                          // wd: 2048x64 dense
        float4 v = ((const float4*)wd)[i];
        ushort4 h; h.x = f2h(v.x); h.y = f2h(v.y); h.z = f2h(v.z); h.w = f2h(v.w);
        ((ushort4*)wdh)[i] = h;
    } else {
        i -= 2195456;                          // wo: 1024x2048
        float4 v = ((const float4*)wo)[i];
        ushort4 h; h.x = f2h(v.x); h.y = f2h(v.y); h.z = f2h(v.z); h.w = f2h(v.w);
        ((ushort4*)woh)[i] = h;
    }
}

// ======== in_proj GEMM: 256x128 tile, 4 waves (wave tile 128x64), 48 KiB LDS ========
// ds_read/MFMA ratio 0.375 (24 b128 reads feed 64 MFMAs per wave-K-step) — DS-pipe
// occupancy per CU drops ~40% vs the 8-wave 128x32-wave-tile variant.
__global__ __launch_bounds__(256, 2) void gemm_inproj(
    const unsigned short* __restrict__ A, const unsigned short* __restrict__ W,
    unsigned short* __restrict__ C, int K, int N, int mtiles, int lda, int ldw)
{
    __shared__ uint4 ldsu4[3072];          // 48 KiB: A[256][64] @0, B[128][64] @32768
    char* lds = (char*)ldsu4;
    const int tid = threadIdx.x;
    const int w = tid >> 6, lane = tid & 63;

    const int nwg = gridDim.x;
    const int cpx = nwg >> 3;
    const int bid = blockIdx.x;
    const int swz = (bid & 7) * cpx + (bid >> 3);
    const int ntiles = nwg / mtiles;
    const int per = 8 * ntiles;
    const int gid = swz / per;
    const int rem = swz - gid * per;
    const int m0 = (gid * 8 + (rem & 7)) * 256;
    const int n0 = (rem >> 3) * 128;

    const int wr = w >> 1, wc = w & 1;     // wave tile: 128 x 64
    const int lm = lane & 15, lk = lane >> 4;

    f32x4 acc[8][4];
#pragma unroll
    for (int i = 0; i < 8; ++i)
#pragma unroll
        for (int j = 0; j < 4; ++j) { acc[i][j][0]=0.f; acc[i][j][1]=0.f; acc[i][j][2]=0.f; acc[i][j][3]=0.f; }

    const int rsub = w * 8 + (lane >> 3);               // 0..31 (row within 32-row issue)
    const int xr8  = ((lane & 7) ^ (lane >> 3)) << 3;   // pre-swizzled col chunk
    const unsigned short* gA = A + (size_t)(m0 + rsub) * lda + xr8;
    const unsigned short* gW = W + (size_t)(n0 + rsub) * ldw + xr8;
    const int sdst = w * 1024;                           // + lane*16 appended by HW

    for (int kt = 0; kt < K; kt += 64) {
#pragma unroll
        for (int i = 0; i < 8; ++i)                      // A: 256 rows, 8 issues x 32 rows
            gload16(gA + (size_t)i * 32 * lda + kt, lds + i * 4096 + sdst);
#pragma unroll
        for (int i = 0; i < 4; ++i)                      // B: 128 rows, 4 issues x 32 rows
            gload16(gW + (size_t)i * 32 * ldw + kt, lds + 32768 + i * 4096 + sdst);
        __syncthreads();
#pragma unroll
        for (int kk = 0; kk < 2; ++kk) {
            half8v b[4];
#pragma unroll
            for (int nb = 0; nb < 4; ++nb) {
                const int br = wc * 64 + nb * 16 + lm;
                b[nb] = *(const half8v*)(lds + 32768 + br * 128 + (((kk * 4 + lk) ^ (br & 7)) << 4));
            }
            __builtin_amdgcn_s_setprio(1);
#pragma unroll
            for (int mb = 0; mb < 8; ++mb) {
                const int ar = wr * 128 + mb * 16 + lm;
                half8v a = *(const half8v*)(lds + ar * 128 + (((kk * 4 + lk) ^ (ar & 7)) << 4));
#pragma unroll
                for (int nb = 0; nb < 4; ++nb)
                    acc[mb][nb] = __builtin_amdgcn_mfma_f32_16x16x32_f16(a, b[nb], acc[mb][nb], 0, 0, 0);
            }
            __builtin_amdgcn_s_setprio(0);
        }
        __syncthreads();
    }

#pragma unroll
    for (int mb = 0; mb < 8; ++mb)
#pragma unroll
        for (int nb = 0; nb < 4; ++nb)
#pragma unroll
            for (int r = 0; r < 4; ++r)
                C[(size_t)(m0 + wr * 128 + mb * 16 + lk * 4 + r) * N + (n0 + wc * 64 + nb * 16 + lm)]
                    = f2h(acc[mb][nb][r]);
}

// ======== out_proj GEMM: 128x64 tile, full K, f32 output (no split-K, no reduce) ========
__global__ __launch_bounds__(256, 4) void gemm_out(
    const unsigned short* __restrict__ A, const unsigned short* __restrict__ W,
    float* __restrict__ C, int K, int N, int mtiles, int lda, int ldw)
{
    __shared__ uint4 ldsu4[1536];          // 24 KiB: A[128][64] @0, W[64][64] @16384
    char* lds = (char*)ldsu4;
    const int tid = threadIdx.x;
    const int w = tid >> 6, lane = tid & 63;

    const int nwg = gridDim.x;             // 512
    const int cpx = nwg >> 3;
    const int bid = blockIdx.x;
    const int swz = (bid & 7) * cpx + (bid >> 3);
    const int ntiles = nwg / mtiles;       // 16
    const int per = 8 * ntiles;            // 128
    const int gid = swz / per;
    const int rem = swz - gid * per;
    const int m0 = (gid * 8 + (rem & 7)) * 128;
    const int n0 = (rem >> 3) * 64;

    const int wr = w >> 1, wc = w & 1;     // wave tile: 64 x 32
    const int lm = lane & 15, lk = lane >> 4;

    f32x4 acc[4][2];
#pragma unroll
    for (int i = 0; i < 4; ++i)
#pragma unroll
        for (int j = 0; j < 2; ++j) { acc[i][j][0]=0.f; acc[i][j][1]=0.f; acc[i][j][2]=0.f; acc[i][j][3]=0.f; }

    const int rloc = w * 8 + (lane >> 3);                // 0..31
    const int xr8  = ((lane & 7) ^ (lane >> 3)) << 3;    // pre-swizzled col chunk
    const unsigned short* gA = A + (size_t)(m0 + rloc) * lda + xr8;
    const unsigned short* gW = W + (size_t)(n0 + rloc) * ldw + xr8;
    const int sdst = w * 1024;                            // + lane*16 appended by HW

    for (int kt = 0; kt < K; kt += 64) {
#pragma unroll
        for (int i = 0; i < 4; ++i)                       // A: 128 rows
            gload16(gA + (size_t)i * 32 * lda + kt, lds + i * 4096 + sdst);
#pragma unroll
        for (int i = 0; i < 2; ++i)                       // W: 64 rows
            gload16(gW + (size_t)i * 32 * ldw + kt, lds + 16384 + i * 4096 + sdst);
        __syncthreads();
#pragma unroll
        for (int kk = 0; kk < 2; ++kk) {
            half8v b[2];
#pragma unroll
            for (int nb = 0; nb < 2; ++nb) {
                const int br = wc * 32 + nb * 16 + lm;
                b[nb] = *(const half8v*)(lds + 16384 + br * 128 + (((kk * 4 + lk) ^ (br & 7)) << 4));
            }
            __builtin_amdgcn_s_setprio(1);
#pragma unroll
            for (int mb = 0; mb < 4; ++mb) {
                const int ar = wr * 64 + mb * 16 + lm;
                half8v a = *(const half8v*)(lds + ar * 128 + (((kk * 4 + lk) ^ (ar & 7)) << 4));
#pragma unroll
                for (int nb = 0; nb < 2; ++nb)
                    acc[mb][nb] = __builtin_amdgcn_mfma_f32_16x16x32_f16(a, b[nb], acc[mb][nb], 0, 0, 0);
            }
            __builtin_amdgcn_s_setprio(0);
        }
        __syncthreads();
    }

#pragma unroll
    for (int mb = 0; mb < 4; ++mb)
#pragma unroll
        for (int nb = 0; nb < 2; ++nb)
#pragma unroll
            for (int r = 0; r < 4; ++r)
                C[(size_t)(m0 + wr * 64 + mb * 16 + lk * 4 + r) * N + (n0 + wc * 32 + nb * 16 + lm)]
                    = acc[mb][nb][r];
}

// ---------------- 128x128 fp16 MFMA GEMM, split-K, fp16 output (xproj / dtproj) --------
#define A_OFF 0
#define W_OFF 16384

__global__ __launch_bounds__(256) void gemm_mfma_h(
    const unsigned short* __restrict__ A, const unsigned short* __restrict__ W,
    unsigned short* __restrict__ C, int K, int ldc, int nmax, int mtiles,
    int sA1, int sA2, int ldw, const float* __restrict__ bias, int kspl, int cstride)
{
    __shared__ uint4 ldsu4[2048];
    char* lds = (char*)ldsu4;
    const int tid  = threadIdx.x;
    const int w    = tid >> 6, lane = tid & 63;

    const int nwg = gridDim.x;
    const int cpx = nwg >> 3;
    const int bid = blockIdx.x;
    const int swz = (bid & 7) * cpx + (bid >> 3);
    const int nbp = nwg / kspl;
    const int ks  = swz / nbp;
    const int tt  = swz - ks * nbp;
    const int ntiles = nbp / mtiles;
    const int per = 8 * ntiles;
    const int gid = tt / per;
    const int rem = tt - gid * per;
    const int m0 = (gid * 8 + (rem & 7)) * 128;
    const int n0 = (rem >> 3) * 128;
    const int kOff = ks * K;

    const int wr = w >> 1, wc = w & 1;

    f32x4 acc[4][4];
#pragma unroll
    for (int i = 0; i < 4; ++i)
#pragma unroll
        for (int j = 0; j < 4; ++j) { acc[i][j][0]=0.f; acc[i][j][1]=0.f; acc[i][j][2]=0.f; acc[i][j][3]=0.f; }

    const int rloc = w * 32 + (lane >> 3);
    const int xr8  = ((lane & 7) ^ (lane >> 3)) << 3;
    const int rowA = m0 + rloc;
    const unsigned short* gA = A + (size_t)(rowA >> 1) * sA2 + (size_t)(rowA & 1) * sA1 + kOff + xr8;
    const unsigned short* gW = W + (size_t)(n0 + rloc) * ldw + kOff + xr8;

    const int lm  = lane & 15;
    const int lk  = lane >> 4;
    const int lk4 = lk * 4;

    for (int kt = 0; kt < K; kt += 64) {
#pragma unroll
        for (int i = 0; i < 4; ++i) {
            const int rb = w * 32 + i * 8;
            gload16(gA + (size_t)i * 4 * sA2 + kt, lds + A_OFF + rb * 128);
            gload16(gW + (size_t)i * 8 * ldw + kt, lds + W_OFF + rb * 128);
        }
        __syncthreads();
#pragma unroll
        for (int h = 0; h < 2; ++h) {
            half8v af[4], wf[4];
            const int ch = h * 4 + lk;
#pragma unroll
            for (int t = 0; t < 4; ++t) {
                const int ar = wr * 64 + t * 16 + lm;
                const int wrw = wc * 64 + t * 16 + lm;
                af[t] = *(const half8v*)(lds + A_OFF + ar * 128 + ((ch ^ (ar & 7)) << 4));
                wf[t] = *(const half8v*)(lds + W_OFF + wrw * 128 + ((ch ^ (wrw & 7)) << 4));
            }
#pragma unroll
            for (int i = 0; i < 4; ++i)
#pragma unroll
                for (int j = 0; j < 4; ++j)
                    acc[i][j] = __builtin_amdgcn_mfma_f32_16x16x32_f16(af[i], wf[j], acc[i][j], 0, 0, 0);
        }
        __syncthreads();
    }

    unsigned short* Cp = C + (size_t)ks * cstride;
    if (bias) {
#pragma unroll
        for (int j = 0; j < 4; ++j) {
            const int n = n0 + wc * 64 + j * 16 + lm;
            const float bv = (n < nmax) ? bias[n] : 0.f;
#pragma unroll
            for (int i = 0; i < 4; ++i)
#pragma unroll
                for (int r = 0; r < 4; ++r) {
                    float v = acc[i][j][r] + bv;
                    if (n < nmax)
                        Cp[(size_t)(m0 + wr * 64 + i * 16 + lk4 + r) * ldc + n] = f2h(softplusf(v));
                }
        }
    } else {
#pragma unroll
        for (int i = 0; i < 4; ++i)
#pragma unroll
            for (int j = 0; j < 4; ++j) {
                const int n = n0 + wc * 64 + j * 16 + lm;
                if (n < nmax)
#pragma unroll
                    for (int r = 0; r < 4; ++r)
                        Cp[(size_t)(m0 + wr * 64 + i * 16 + lk4 + r) * ldc + n] = f2h(acc[i][j][r]);
            }
    }
}

// xproj reduce: sum 8 fp16 partials; cols 0..63 -> dlh fp16, cols 64..95 -> xdbl f32
__global__ __launch_bounds__(256) void xproj_reduce_k(
    const unsigned short* __restrict__ part, float* __restrict__ xdbl,
    unsigned short* __restrict__ dlh)
{
    int i = blockIdx.x * 256 + threadIdx.x;   // NROWS*32 quads
    if (i >= NROWS * 32) return;
    int row = i >> 5, q = i & 31;
    float s0 = 0.f, s1 = 0.f, s2 = 0.f, s3 = 0.f;
#pragma unroll
    for (int ks = 0; ks < 8; ++ks) {
        ushort4 v = *(const ushort4*)(part + (size_t)ks * (NROWS * 128) + (size_t)row * 128 + q * 4);
        s0 += h2f(v.x); s1 += h2f(v.y); s2 += h2f(v.z); s3 += h2f(v.w);
    }
    if (q < 16) {
        ushort4 h; h.x = f2h(s0); h.y = f2h(s1); h.z = f2h(s2); h.w = f2h(s3);
        *(ushort4*)(dlh + (size_t)row * 64 + q * 4) = h;
    } else {
        *(float4*)(xdbl + (size_t)row * 96 + q * 4) = make_float4(s0, s1, s2, s3);
    }
}

// ---------------- causal depthwise conv(4) + bias + SiLU, fp16 in -> fp16 out ----------
__global__ __launch_bounds__(256) void conv_silu_k(
    const unsigned short* __restrict__ xzh, const float* __restrict__ cw,
    const float* __restrict__ cb, unsigned short* __restrict__ xch)
{
    int i = blockIdx.x * 256 + threadIdx.x;   // NROWS*256
    int d8 = (i & 255) << 3;
    int row = i >> 8;
    int l = row & (SEQ - 1);
    const unsigned short* base = xzh + (size_t)row * 4096 + d8;
    ushort8v x0 = *(const ushort8v*)base;
    ushort8v x1 = {}, x2 = {}, x3 = {};
    if (l >= 1) x1 = *(const ushort8v*)(base - 4096);
    if (l >= 2) x2 = *(const ushort8v*)(base - 8192);
    if (l >= 3) x3 = *(const ushort8v*)(base - 12288);
    ushort8v out;
#pragma unroll
    for (int j = 0; j < 8; ++j) {
        float4 wv = *(const float4*)(cw + (size_t)(d8 + j) * 4);
        float a = cb[d8 + j];
        a = fmaf(h2f(x3[j]), wv.x, a);
        a = fmaf(h2f(x2[j]), wv.y, a);
        a = fmaf(h2f(x1[j]), wv.z, a);
        a = fmaf(h2f(x0[j]), wv.w, a);
        out[j] = f2h(a * sigf(a));
    }
    *(ushort8v*)(xch + (size_t)row * DIN + d8) = out;
}

// ---------------- chunked selective scan: register-resident 16-state, fp16 states ------
__global__ __launch_bounds__(256) void scan_pass1(
    const unsigned short* __restrict__ dth, const unsigned short* __restrict__ xch,
    const float* __restrict__ xdbl, const float* __restrict__ Alog,
    unsigned short* __restrict__ hbuf, unsigned short* __restrict__ apbuf)
{
    const int b = blockIdx.z, c = blockIdx.y;
    const int d = blockIdx.x * 256 + threadIdx.x;
    float A[16];
#pragma unroll
    for (int q = 0; q < 4; ++q) *(float4*)&A[q * 4] = *(const float4*)&Alog[(size_t)d * 16 + q * 4];
    bool seq = true;
#pragma unroll
    for (int n = 0; n < 16; ++n) {
        A[n] = -__expf(A[n]);
        seq = seq && (fabsf(A[n] + (float)(n + 1)) < 1e-5f * (float)(n + 1));
    }
    float h[16] = {};
    float sumdt = 0.f;
    const int rowbase = b * SEQ + c * CHL;
    int row = rowbase;
    float dtv = h2f(dth[(size_t)row * DIN + d]);
    float xcv = h2f(xch[(size_t)row * DIN + d]);
    if (seq) {
        for (int t = 0; t < CHL; ++t) {
            const int nrow = row + ((t + 1) < CHL ? 1 : 0);
            float dtv2 = h2f(dth[(size_t)nrow * DIN + d]);
            float xcv2 = h2f(xch[(size_t)nrow * DIN + d]);
            const float* xr = xdbl + (size_t)row * 96;
            float u = dtv * xcv;
            sumdt += dtv;
            float r = __expf(-dtv);
            float dA = r;
#pragma unroll
            for (int n = 0; n < 16; ++n) {
                h[n] = fmaf(dA, h[n], u * xr[64 + n]);
                dA *= r;
            }
            dtv = dtv2; xcv = xcv2; row = nrow;
        }
    } else {
        for (int t = 0; t < CHL; ++t) {
            const int nrow = row + ((t + 1) < CHL ? 1 : 0);
            float dtv2 = h2f(dth[(size_t)nrow * DIN + d]);
            float xcv2 = h2f(xch[(size_t)nrow * DIN + d]);
            const float* xr = xdbl + (size_t)row * 96;
            float u = dtv * xcv;
            sumdt += dtv;
#pragma unroll
            for (int n = 0; n < 16; ++n) {
                float dA = __expf(dtv * A[n]);
                h[n] = fmaf(dA, h[n], u * xr[64 + n]);
            }
            dtv = dtv2; xcv = xcv2; row = nrow;
        }
    }
    float ap[16];
    if (seq) {
        float R = __expf(-sumdt);
        float a = R;
#pragma unroll
        for (int n = 0; n < 16; ++n) { ap[n] = a; a *= R; }
    } else {
#pragma unroll
        for (int n = 0; n < 16; ++n) ap[n] = __expf(sumdt * A[n]);
    }
    size_t e = ((size_t)(b * NCH + c) << 15) + (size_t)d * 16;
    ushort8v hv0, hv1, av0, av1;
#pragma unroll
    for (int n = 0; n < 8; ++n) {
        hv0[n] = f2h(h[n]);  hv1[n] = f2h(h[8 + n]);
        av0[n] = f2h(ap[n]); av1[n] = f2h(ap[8 + n]);
    }
    *(ushort8v*)(hbuf + e)      = hv0;
    *(ushort8v*)(hbuf + e + 8)  = hv1;
    *(ushort8v*)(apbuf + e)     = av0;
    *(ushort8v*)(apbuf + e + 8) = av1;
}

__global__ __launch_bounds__(256) void scan_pass2(
    unsigned short* __restrict__ hbuf, const unsigned short* __restrict__ apbuf)
{
    int idx = blockIdx.x * 256 + threadIdx.x;   // 65536
    int b = idx >> 15;
    int dn = idx & 32767;
    float carry = 0.f;
    for (int c = 0; c < NCH; ++c) {
        size_t e = ((size_t)(b * NCH + c) << 15) + dn;
        float hl = h2f(hbuf[e]);
        float ap = h2f(apbuf[e]);
        hbuf[e] = f2h(carry);
        carry = fmaf(ap, carry, hl);
    }
}

// pass 3: re-scan from h_in (fp16); fused epilogue writes op fp16 (dense [4096][2048])
__global__ __launch_bounds__(256) void scan_pass3(
    const unsigned short* __restrict__ dth, const unsigned short* __restrict__ xch,
    const unsigned short* __restrict__ xzh, const float* __restrict__ xdbl,
    const float* __restrict__ Alog, const float* __restrict__ Dp,
    const unsigned short* __restrict__ hbuf, unsigned short* __restrict__ oph)
{
    const int b = blockIdx.z, c = blockIdx.y;
    const int d = blockIdx.x * 256 + threadIdx.x;
    float A[16];
#pragma unroll
    for (int q = 0; q < 4; ++q) *(float4*)&A[q * 4] = *(const float4*)&Alog[(size_t)d * 16 + q * 4];
    bool seq = true;
#pragma unroll
    for (int n = 0; n < 16; ++n) {
        A[n] = -__expf(A[n]);
        seq = seq && (fabsf(A[n] + (float)(n + 1)) < 1e-5f * (float)(n + 1));
    }
    float h[16];
    size_t e = ((size_t)(b * NCH + c) << 15) + (size_t)d * 16;
    {
        ushort8v hv0 = *(const ushort8v*)(hbuf + e);
        ushort8v hv1 = *(const ushort8v*)(hbuf + e + 8);
#pragma unroll
        for (int n = 0; n < 8; ++n) { h[n] = h2f(hv0[n]); h[8 + n] = h2f(hv1[n]); }
    }
    const float Dd = Dp[d];
    const int rowbase = b * SEQ + c * CHL;
    int row = rowbase;
    float dtv = h2f(dth[(size_t)row * DIN + d]);
    float xcv = h2f(xch[(size_t)row * DIN + d]);
    float zv  = h2f(xzh[(size_t)row * 4096 + DIN + d]);
    if (seq) {
        for (int t = 0; t < CHL; ++t) {
            const int nrow = row + ((t + 1) < CHL ? 1 : 0);
            float dtv2 = h2f(dth[(size_t)nrow * DIN + d]);
            float xcv2 = h2f(xch[(size_t)nrow * DIN + d]);
            float zv2  = h2f(xzh[(size_t)nrow * 4096 + DIN + d]);
            const float* xr = xdbl + (size_t)row * 96;
            float u = dtv * xcv;
            float r = __expf(-dtv);
            float dA = r;
            float y = 0.f;
#pragma unroll
            for (int n = 0; n < 16; ++n) {
                h[n] = fmaf(dA, h[n], u * xr[64 + n]);
                y = fmaf(h[n], xr[80 + n], y);
                dA *= r;
            }
            float val = (y + xcv * Dd) * zv * sigf(zv);
            oph[(size_t)row * DIN + d] = f2h(val);
            dtv = dtv2; xcv = xcv2; zv = zv2; row = nrow;
        }
    } else {
        for (int t = 0; t < CHL; ++t) {
            const int nrow = row + ((t + 1) < CHL ? 1 : 0);
            float dtv2 = h2f(dth[(size_t)nrow * DIN + d]);
            float xcv2 = h2f(xch[(size_t)nrow * DIN + d]);
            float zv2  = h2f(xzh[(size_t)nrow * 4096 + DIN + d]);
            const float* xr = xdbl + (size_t)row * 96;
            float u = dtv * xcv;
            float y = 0.f;
#pragma unroll
            for (int n = 0; n < 16; ++n) {
                float dA = __expf(dtv * A[n]);
                h[n] = fmaf(dA, h[n], u * xr[64 + n]);
                y = fmaf(h[n], xr[80 + n], y);
            }
            float val = (y + xcv * Dd) * zv * sigf(zv);
            oph[(size_t)row * DIN + d] = f2h(val);
            dtv = dtv2; xcv = xcv2; zv = zv2; row = nrow;
        }
    }
}

extern "C" void kernel_launch(void* const* d_in, const int* in_sizes, int n_in,
                              void* d_out, int out_size, void* d_ws, size_t ws_size,
                              hipStream_t stream)
{
    const float* x    = (const float*)d_in[0];
    const float* wi   = (const float*)d_in[1];
    const float* cw   = (const float*)d_in[2];
    const float* cb   = (const float*)d_in[3];
    const float* wx   = (const float*)d_in[4];
    const float* wd   = (const float*)d_in[5];
    const float* bd   = (const float*)d_in[6];
    const float* alog = (const float*)d_in[7];
    const float* Dp   = (const float*)d_in[8];
    const float* wo   = (const float*)d_in[9];
    float* out = (float*)d_out;

    float* wsf  = (float*)d_ws;
    float* xzr  = wsf;                          // region 16,777,216 f32
    float* xcr  = wsf + 16777216;               // region  8,388,608 f32
    float* xdbl = wsf + 25165824;               // [4096][96] f32
    float* dtr  = wsf + 25559040;               // region  8,388,608 f32

    // xz region: fp16 xz [4096][4096] in first half; oph + hbuf in the second half
    unsigned short* xzh = (unsigned short*)xzr;
    float* scr = xzr + 8388608;
    unsigned short* oph  = (unsigned short*)scr;                // [4096][2048] fp16
    unsigned short* hbuf = (unsigned short*)(scr + 4194304);    // 4,194,304 fp16 (NCH=64)

    // xc region: xch fp16 first half; apbuf above it
    unsigned short* xh    = (unsigned short*)xcr;               // in_proj A; dead after gemm
    unsigned short* xch   = (unsigned short*)xcr;               // conv output (overwrites xh)
    unsigned short* apbuf = (unsigned short*)(xcr + 4194304);   // 4,194,304 fp16 (NCH=64)

    // dt region (sequential lifetimes, all offsets in f32 units):
    unsigned short* wih    = (unsigned short*)dtr;               // [0,4.19M) in_proj W; dead after gemm
    unsigned short* dth    = (unsigned short*)dtr;               // [0,4.19M) dt fp16; dead after pass3
    unsigned short* wxh    = (unsigned short*)(dtr + 4194304);   // [4.19M,4.33M) padded Wx
    unsigned short* xparth = (unsigned short*)(dtr + 4325376);   // [4.33M,6.42M) xproj partials
    unsigned short* woh    = (unsigned short*)(dtr + 6422528);   // [6.42M,7.47M) wo fp16
    unsigned short* wdh    = (unsigned short*)(dtr + 7471104);   // [7.47M,7.54M) wd fp16
    unsigned short* dlh    = (unsigned short*)(dtr + 7536640);   // [7.54M,7.67M) dt_low fp16

    // 1) fp16 operands: x, wi, Wx(pad), wd, wo
    cvt_in_k<<<10624, 256, 0, stream>>>(x, wi, wx, wd, wo, xh, wih, wxh, wdh, woh);
    // 2) xz = x @ in_proj_w^T  -> fp16 (M=4096, N=4096, K=1024), wide wave tile
    gemm_inproj<<<512, 256, 0, stream>>>(xh, wih, xzh, 1024, 4096, 16, 1024, 1024);
    // 3) xch = fp16 silu(conv(xs)+b)  (overwrites xh — dead)
    conv_silu_k<<<4096, 256, 0, stream>>>(xzh, cw, cb, xch);
    // 4) x_dbl = xch @ Wx^T, split-K 8x256 -> fp16 partials; reduce -> xdbl f32 + dlh fp16
    gemm_mfma_h<<<256, 256, 0, stream>>>(xch, wxh, xparth, 256, 128, 128, 32, 2048, 4096, 2048,
                                         nullptr, 8, NROWS * 128);
    xproj_reduce_k<<<512, 256, 0, stream>>>(xparth, xdbl, dlh);
    // 5) dt = fp16 softplus(dt_low @ Wd^T + bd)
    gemm_mfma_h<<<512, 256, 0, stream>>>(dlh, wdh, dth, 64, 2048, 2048, 32, 64, 128, 64,
                                         bd, 1, 0);
    // 6) chunked scan (NCH=64, CHL=32, fp16 chunk states); pass3 writes op fp16 dense
    scan_pass1<<<dim3(8, NCH, 2), 256, 0, stream>>>(dth, xch, xdbl, alog, hbuf, apbuf);
    scan_pass2<<<256, 256, 0, stream>>>(hbuf, apbuf);
    scan_pass3<<<dim3(8, NCH, 2), 256, 0, stream>>>(dth, xch, xzh, xdbl, alog, Dp, hbuf, oph);
    // 7) out = op @ out_proj_w^T (M=4096, N=1024, K=2048), 128x64 tiles, f32 out direct
    gemm_out<<<512, 256, 0, stream>>>(oph, woh, out, 2048, 1024, 32, 2048, 2048);
}